// Round 8
// baseline (535.371 us; speedup 1.0000x reference)
//
#include <hip/hip_runtime.h>
#include <cstdint>
#include <cstddef>

#define B_   8
#define S_   2048
#define DIN_ 1024
#define H_   1024
#define V_   50257

typedef unsigned short ushort_t;
typedef __bf16 bf16x8 __attribute__((ext_vector_type(8)));
typedef float  f32x4  __attribute__((ext_vector_type(4)));

__device__ __forceinline__ ushort_t f2bf(float x) {
    unsigned u = __float_as_uint(x);
    u = (u + 0x7fffu + ((u >> 16) & 1u)) >> 16;
    return (ushort_t)u;
}

__device__ __forceinline__ void async16(const void* g, void* s) {
    __builtin_amdgcn_global_load_lds(
        (const __attribute__((address_space(1))) unsigned int*)g,
        (__attribute__((address_space(3))) unsigned int*)s, 16, 0, 0);
}

__device__ __forceinline__ float wredmax(float v) {
#pragma unroll
    for (int o = 32; o; o >>= 1) v = fmaxf(v, __shfl_xor(v, o));
    return v;
}
__device__ __forceinline__ float wredsum(float v) {
#pragma unroll
    for (int o = 32; o; o >>= 1) v += __shfl_xor(v, o);
    return v;
}

// ---------------- elementwise / setup ----------------
__global__ void f2bf_vec(const float* __restrict__ in, ushort_t* __restrict__ out, int n4) {
    int i = blockIdx.x * 256 + threadIdx.x;
    if (i >= n4) return;
    float4 f = ((const float4*)in)[i];
    ushort4 u;
    u.x = f2bf(f.x); u.y = f2bf(f.y); u.z = f2bf(f.z); u.w = f2bf(f.w);
    ((ushort4*)out)[i] = u;
}

// Wq|Wk|Wv (each 1024x1024 fp32) -> wqkv_bf (3*1048576 bf16)
__global__ void f2bf_w3(const float* __restrict__ Wq, const float* __restrict__ Wk,
                        const float* __restrict__ Wv, ushort_t* __restrict__ out) {
    int i = blockIdx.x * 256 + threadIdx.x;  // 0..786431 (float4 units)
    int w = i >> 18, off = i & 262143;
    const float* src = w == 0 ? Wq : (w == 1 ? Wk : Wv);
    float4 f = ((const float4*)src)[off];
    ushort4 u;
    u.x = f2bf(f.x); u.y = f2bf(f.y); u.z = f2bf(f.z); u.w = f2bf(f.w);
    ((ushort4*)(out + (size_t)w * 1048576))[off] = u;
}

__global__ void pos_bias_kernel(float* __restrict__ bias) {
    int k = blockIdx.x * 256 + threadIdx.x;
    if (k >= S_) return;
    float ang = 6.283185307179586f * (float)k / 1024.0f;
    float b = 0.f;
    b += sinf(1.f * ang) + cosf(1.f * ang);
    b += sinf(2.f * ang) + cosf(2.f * ang);
    b += sinf(4.f * ang) + cosf(4.f * ang);
    bias[k] = b;
}

// Wt[1024k][1024i] fp32 -> wtT[1024i][1024k] bf16
__global__ __launch_bounds__(256)
void transpose_wt(const float* __restrict__ Wt, ushort_t* __restrict__ wtT) {
    __shared__ float t[64][65];
    int k0 = blockIdx.x * 64, i0 = blockIdx.y * 64;
    int tx = threadIdx.x & 63, ty = threadIdx.x >> 6;
#pragma unroll
    for (int j = 0; j < 16; j++) {
        int k = ty * 16 + j;
        t[k][tx] = Wt[(size_t)(k0 + k) * DIN_ + i0 + tx];
    }
    __syncthreads();
#pragma unroll
    for (int j = 0; j < 16; j++) {
        int i = ty * 16 + j;
        wtT[(size_t)(i0 + i) * H_ + k0 + tx] = f2bf(t[tx][i]);
    }
}

// b_comb[j] = b{q,k,v}[j%1024] + dot(W{q,k,v}[j%1024], bt)
__global__ __launch_bounds__(256)
void bcomb_kernel(const float* __restrict__ Wq, const float* __restrict__ Wk,
                  const float* __restrict__ Wv, const float* __restrict__ bq,
                  const float* __restrict__ bk, const float* __restrict__ bv,
                  const float* __restrict__ bt, float* __restrict__ bcomb) {
    int wave = threadIdx.x >> 6, lane = threadIdx.x & 63;
    int j = blockIdx.x * 4 + wave;
    const float* W  = j < 1024 ? Wq : (j < 2048 ? Wk : Wv);
    const float* bb = j < 1024 ? bq : (j < 2048 ? bk : bv);
    int rowj = j & 1023;
    const float4* wr4 = (const float4*)(W + (size_t)rowj * 1024);
    const float4* bt4 = (const float4*)bt;
    float s = 0.f;
#pragma unroll
    for (int c = 0; c < 4; c++) {
        float4 w = wr4[c * 64 + lane];
        float4 b = bt4[c * 64 + lane];
        s += w.x * b.x + w.y * b.y + w.z * b.z + w.w * b.w;
    }
    s = wredsum(s);
    if (lane == 0) bcomb[j] = s + bb[rowj];
}

// ---------------- 128^2 m97-structure GEMM — small GEMMs ----------------
template <int OUT_BF16>
__global__ __launch_bounds__(256)
void gemm_bt(const ushort_t* __restrict__ A, int lda,
             const ushort_t* __restrict__ Bt, int ldb,
             void* __restrict__ Cv, int ldc, int K, const float* __restrict__ bias) {
    int bn = blockIdx.x, bm = blockIdx.y;
    __shared__ ushort_t As[128 * 32];
    __shared__ ushort_t Bs[128 * 32];
    int tid = threadIdx.x, wave = tid >> 6, lane = tid & 63;
    int wr = wave >> 1, wc = wave & 1;
    int nkt = K >> 5;
    int srow = lane >> 2, scol = (lane & 3) * 8;
    size_t arow0 = (size_t)bm * 128, brow0 = (size_t)bn * 128;
    f32x4 acc[4][4];
#pragma unroll
    for (int m = 0; m < 4; m++)
#pragma unroll
        for (int n = 0; n < 4; n++) acc[m][n] = f32x4{0.f, 0.f, 0.f, 0.f};
    for (int kt = 0; kt < nkt; ++kt) {
        int k0 = kt * 32;
#pragma unroll
        for (int i = 0; i < 2; i++) {
            int reg = wave * 2 + i;
            int row = reg * 16 + srow;
            async16(A + (arow0 + row) * (size_t)lda + k0 + scol, (ushort_t*)As + reg * 512);
            async16(Bt + (brow0 + row) * (size_t)ldb + k0 + scol, (ushort_t*)Bs + reg * 512);
        }
        __syncthreads();
        bf16x8 af[4], bfr[4];
#pragma unroll
        for (int m = 0; m < 4; m++)
            af[m] = *(const bf16x8*)&As[(wr * 64 + m * 16 + (lane & 15)) * 32 + (lane >> 4) * 8];
#pragma unroll
        for (int n = 0; n < 4; n++)
            bfr[n] = *(const bf16x8*)&Bs[(wc * 64 + n * 16 + (lane & 15)) * 32 + (lane >> 4) * 8];
#pragma unroll
        for (int m = 0; m < 4; m++)
#pragma unroll
            for (int n = 0; n < 4; n++)
                acc[m][n] = __builtin_amdgcn_mfma_f32_16x16x32_bf16(af[m], bfr[n], acc[m][n], 0, 0, 0);
        __syncthreads();
    }
    int rl = (lane >> 4) * 4, cl = lane & 15;
#pragma unroll
    for (int m = 0; m < 4; m++)
#pragma unroll
        for (int n = 0; n < 4; n++) {
            int col = bn * 128 + wc * 64 + n * 16 + cl;
            float badd = bias ? bias[col] : 0.f;
#pragma unroll
            for (int r = 0; r < 4; r++) {
                int row = bm * 128 + wr * 64 + m * 16 + rl + r;
                float v = acc[m][n][r] + badd;
                size_t off = (size_t)row * ldc + col;
                if (OUT_BF16) ((ushort_t*)Cv)[off] = f2bf(v);
                else          ((float*)Cv)[off] = v;
            }
        }
}

// ---------------- 256^2 m201-template 8-phase GEMM ----------------
// MODE 0: plain (QKV). MODE 1: causal-packed lower-triangle (scores).
// MODE 2: PV K-split (A-set x<32 K<=1024 -> Cv; B-set x>=32 K in
//         [1024,(bm+1)*256) descending-K -> Cv2). All nkt even (4..16).
// Faithful m201 structure: per phase {reads(12/8/4/0) | stage 1 half |
// BARRIER | lgkmcnt(0) | setprio(1) 16xMFMA setprio(0) | BARRIER}; the
// barrier between read-issue and lgkm-wait is the latency window. 8 phases
// per 2 K-tiles (even tiles buf0, odd buf1). Stage order Bh0(u+1),Bh1(u+1),
// Ah0(u+2),Ah1(u+2),Bh0(u+2),Bh1(u+2),Ah0(u+3),Ah1(u+3); each region freed
// 2 barriers before its stage. vmcnt(4) only at ph4/ph8 (confirms next
// tile's 4 halves, keeps 4 loads in flight); vmcnt(0) in last iteration.
// Swizzle: 16B-slot ^= (row&7) (2-way, free); inverse on global source.
template <int OUT_BF16, int MODE>
__global__ __launch_bounds__(512, 2)
void gemm256(const ushort_t* __restrict__ A, size_t sAb, int lda,
             const ushort_t* __restrict__ Bt, size_t sBb, int ldb,
             void* __restrict__ Cv, size_t sCb, int ldc,
             int K, const float* __restrict__ bias, int nbn, int nwg,
             float* __restrict__ Cv2) {
    extern __shared__ char lds[];
    int bz = blockIdx.y;
    int bm, bn, koff = 0, nkt;
    void* Cuse = Cv;
    size_t sCuse = sCb;
    if (MODE == 2) {
        int x = blockIdx.x;  // 0..47
        if (x < 32) {
            bm = x >> 2; bn = x & 3;
            int km = (bm + 1) * 256; if (km > 1024) km = 1024;
            nkt = km >> 6;
        } else {
            int j = x - 32;
            bm = 7 - (j >> 2); bn = j & 3;           // descending-K order
            koff = 1024;
            nkt = ((bm + 1) * 256 - 1024) >> 6;
            Cuse = Cv2;                               // pre-offset by -1024*ldc
            sCuse = (size_t)1024 * 1024;
        }
    } else {
        int orig = blockIdx.x;
        int qq = nwg >> 3, rr8 = nwg & 7;
        int xcd = orig & 7, bidx = orig >> 3;
        int wgid = (xcd < rr8 ? xcd * (qq + 1) : rr8 * (qq + 1) + (xcd - rr8) * qq) + bidx;
        if (MODE == 1) {  // lower-triangle pack: wgid in [0,36)
            int w = wgid;
            bm = 0;
            while ((bm + 1) * (bm + 2) / 2 <= w) bm++;
            bn = w - bm * (bm + 1) / 2;
        } else {
            bm = wgid / nbn; bn = wgid - bm * nbn;
        }
        nkt = K >> 6;
    }

    const ushort_t* Ab = A + (size_t)bz * sAb;
    const ushort_t* Bb = Bt + (size_t)bz * sBb;
    int tid = threadIdx.x, wave = tid >> 6, lane = tid & 63;
    int wr = wave >> 2, wc = wave & 3;

    // ---- staging addressing (inverse-swizzled global source) ----
    int srow = wave * 8 + (lane >> 3);            // 0..63
    int sswz = ((lane & 7) ^ (lane >> 3)) * 8;    // k-elem offset
    const ushort_t* Ag = Ab + ((size_t)bm * 256 + srow) * (size_t)lda + sswz + koff;
    const ushort_t* Bg = Bb + ((size_t)bn * 256 + srow) * (size_t)ldb + sswz + koff;
    int sdst = wave * 1024;

    // ---- frag read addressing (swizzled) ----
    int fr = lane & 15, g = lane >> 4;
    int kx = (fr >> 2) & 1;
    int gsw = (g ^ (fr & 3)) * 16;
    int aoff = wr * 16384 + fr * 128 + gsw;                    // + buf + mf*2048 + ks
    int boff = 32768 + (wc >> 1) * 16384 + ((wc & 1) * 64 + fr) * 128 + gsw;
    int ks0 = kx << 6, ks1 = (kx ^ 1) << 6;

    f32x4 acc[8][4];
#pragma unroll
    for (int m = 0; m < 8; m++)
#pragma unroll
        for (int n = 0; n < 4; n++) acc[m][n] = f32x4{0.f, 0.f, 0.f, 0.f};

#define STG_A(t, h, bo)                                                        \
    do {                                                                       \
        async16(Ag + (size_t)((h) * 128) * lda + (t) * 64,                     \
                lds + (bo) + (h) * 16384 + sdst);                              \
        async16(Ag + (size_t)((h) * 128 + 64) * lda + (t) * 64,                \
                lds + (bo) + (h) * 16384 + 8192 + sdst);                       \
    } while (0)
#define STG_B(t, h, bo)                                                        \
    do {                                                                       \
        async16(Bg + (size_t)((h) * 128) * ldb + (t) * 64,                     \
                lds + (bo) + 32768 + (h) * 16384 + sdst);                      \
        async16(Bg + (size_t)((h) * 128 + 64) * ldb + (t) * 64,                \
                lds + (bo) + 32768 + (h) * 16384 + 8192 + sdst);               \
    } while (0)
#define RD_A(DST, BUF, MOFS)                                                   \
    _Pragma("unroll")                                                          \
    for (int mf = 0; mf < 4; mf++) {                                           \
        DST[mf][0] = *(const bf16x8*)(lds + (BUF) + aoff + (mf + (MOFS)) * 2048 + ks0); \
        DST[mf][1] = *(const bf16x8*)(lds + (BUF) + aoff + (mf + (MOFS)) * 2048 + ks1); \
    }
#define RD_B(DST, BUF, NOFS)                                                   \
    _Pragma("unroll")                                                          \
    for (int nf = 0; nf < 2; nf++) {                                           \
        DST[nf][0] = *(const bf16x8*)(lds + (BUF) + boff + (nf + (NOFS)) * 2048 + ks0); \
        DST[nf][1] = *(const bf16x8*)(lds + (BUF) + boff + (nf + (NOFS)) * 2048 + ks1); \
    }
#define MMQ(AF, BF, MO, NO)                                                    \
    _Pragma("unroll")                                                          \
    for (int mf = 0; mf < 4; mf++)                                             \
        _Pragma("unroll")                                                      \
        for (int nf = 0; nf < 2; nf++) {                                       \
            acc[mf + (MO)][nf + (NO)] = __builtin_amdgcn_mfma_f32_16x16x32_bf16(AF[mf][0], BF[nf][0], acc[mf + (MO)][nf + (NO)], 0, 0, 0); \
            acc[mf + (MO)][nf + (NO)] = __builtin_amdgcn_mfma_f32_16x16x32_bf16(AF[mf][1], BF[nf][1], acc[mf + (MO)][nf + (NO)], 0, 0, 0); \
        }
#define SB __builtin_amdgcn_sched_barrier(0)
#define PH_PRE                                                                 \
    SB; __builtin_amdgcn_s_barrier();                                          \
    asm volatile("s_waitcnt lgkmcnt(0)" ::: "memory");                         \
    SB; __builtin_amdgcn_s_setprio(1)
#define PH_POST                                                                \
    __builtin_amdgcn_s_setprio(0); SB; __builtin_amdgcn_s_barrier(); SB

    // ---- prologue: tile0 4 halves + tile1 A halves (12 loads); confirm tile0 ----
    STG_A(0, 0, 0); STG_A(0, 1, 0); STG_B(0, 0, 0); STG_B(0, 1, 0);
    STG_A(1, 0, 65536); STG_A(1, 1, 65536);
    asm volatile("s_waitcnt vmcnt(4)" ::: "memory");
    SB; __builtin_amdgcn_s_barrier(); SB;

    bf16x8 a03[4][2], a47[4][2], b01[2][2], b23[2][2];

    int niter = nkt >> 1;
    for (int i = 0; i < niter; ++i) {
        int u = 2 * i;
        bool lastp = (u + 2 >= nkt);

        // ph1: rd A03(u),B01(u)@buf0 | stg Bh0(u+1)->buf1 | Q0
        RD_A(a03, 0, 0); RD_B(b01, 0, 0);
        STG_B(u + 1, 0, 65536);
        PH_PRE; MMQ(a03, b01, 0, 0); PH_POST;

        // ph2: rd A47(u)@buf0 | stg Bh1(u+1)->buf1 | Q1
        RD_A(a47, 0, 4);
        STG_B(u + 1, 1, 65536);
        PH_PRE; MMQ(a47, b01, 4, 0); PH_POST;

        // ph3: rd B23(u)@buf0 | stg Ah0(u+2)->buf0 | Q2
        RD_B(b23, 0, 2);
        if (!lastp) STG_A(u + 2, 0, 0);
        PH_PRE; MMQ(a03, b23, 0, 2); PH_POST;

        // ph4: stg Ah1(u+2)->buf0 | vmcnt | Q3
        if (!lastp) STG_A(u + 2, 1, 0);
        SB;
        if (!lastp) { asm volatile("s_waitcnt vmcnt(4)" ::: "memory"); }
        else        { asm volatile("s_waitcnt vmcnt(0)" ::: "memory"); }
        SB; __builtin_amdgcn_s_barrier(); SB;
        __builtin_amdgcn_s_setprio(1);
        MMQ(a47, b23, 4, 2);
        PH_POST;

        // ph5: rd A03(u+1),B01(u+1)@buf1 | stg Bh0(u+2)->buf0 | Q0'
        RD_A(a03, 65536, 0); RD_B(b01, 65536, 0);
        if (!lastp) STG_B(u + 2, 0, 0);
        PH_PRE; MMQ(a03, b01, 0, 0); PH_POST;

        // ph6: rd A47(u+1)@buf1 | stg Bh1(u+2)->buf0 | Q1'
        RD_A(a47, 65536, 4);
        if (!lastp) STG_B(u + 2, 1, 0);
        PH_PRE; MMQ(a47, b01, 4, 0); PH_POST;

        // ph7: rd B23(u+1)@buf1 | stg Ah0(u+3)->buf1 | Q2'
        RD_B(b23, 65536, 2);
        if (!lastp) STG_A(u + 3, 0, 65536);
        PH_PRE; MMQ(a03, b23, 0, 2); PH_POST;

        // ph8: stg Ah1(u+3)->buf1 | vmcnt | Q3'
        if (!lastp) STG_A(u + 3, 1, 65536);
        SB;
        if (!lastp) { asm volatile("s_waitcnt vmcnt(4)" ::: "memory"); }
        else        { asm volatile("s_waitcnt vmcnt(0)" ::: "memory"); }
        SB; __builtin_amdgcn_s_barrier(); SB;
        __builtin_amdgcn_s_setprio(1);
        MMQ(a47, b23, 4, 2);
        PH_POST;
    }
#undef STG_A
#undef STG_B
#undef RD_A
#undef RD_B
#undef MMQ
#undef SB
#undef PH_PRE
#undef PH_POST

    int rl = (lane >> 4) * 4, cl = lane & 15;
#pragma unroll
    for (int mf = 0; mf < 8; mf++)
#pragma unroll
        for (int nf = 0; nf < 4; nf++) {
            int col = bn * 256 + wc * 64 + nf * 16 + cl;
            float badd = bias ? bias[col] : 0.f;
#pragma unroll
            for (int r = 0; r < 4; r++) {
                int row = bm * 256 + wr * 128 + mf * 16 + rl + r;
                float v = acc[mf][nf][r] + badd;
                size_t off = (size_t)bz * sCuse + (size_t)row * ldc + col;
                if (OUT_BF16) ((ushort_t*)Cuse)[off] = f2bf(v);
                else          ((float*)Cuse)[off] = v;
            }
        }
}

// ---------------- transpose V: qkv[b][s][2048+h] -> vT[b][h][s] ----------------
__global__ __launch_bounds__(256)
void transpose_v(const ushort_t* __restrict__ qkv, ushort_t* __restrict__ vT) {
    __shared__ ushort_t t[64][66];
    int b = blockIdx.z;
    int s0 = blockIdx.x * 64, h0 = blockIdx.y * 64;
    int tx = threadIdx.x & 63, ty = threadIdx.x >> 6;
#pragma unroll
    for (int i = 0; i < 16; i++) {
        int s = ty * 16 + i;
        t[s][tx] = qkv[((size_t)b * S_ + s0 + s) * 3072 + 2048 + h0 + tx];
    }
    __syncthreads();
#pragma unroll
    for (int i = 0; i < 16; i++) {
        int h = ty * 16 + i;
        vT[((size_t)b * H_ + h0 + h) * S_ + s0 + tx] = t[tx][h];
    }
}

// ---------------- softmax rows ----------------
__global__ __launch_bounds__(256)
void softmax_kernel(const float* __restrict__ scores, ushort_t* __restrict__ P,
                    const float* __restrict__ bias) {
    __shared__ float srs[S_];
    __shared__ float red[8];
    int q = blockIdx.x, b = blockIdx.y;
    int L = q + 1;
    int tid = threadIdx.x;
    const float* srow = scores + ((size_t)b * S_ + q) * S_;
    const float scale = 0.03125f;

    float lm = -3e38f;
    for (int k = tid; k < L; k += 256) {
        float s = srow[k] * scale + bias[k];
        srs[k] = s;
        lm = fmaxf(lm, s);
    }
    lm = wredmax(lm);
    if ((tid & 63) == 0) red[tid >> 6] = lm;
    __syncthreads();
    float m = fmaxf(fmaxf(red[0], red[1]), fmaxf(red[2], red[3]));

    float ls = 0.f;
    for (int k = tid; k < L; k += 256) {
        float e = __expf(srs[k] - m);
        srs[k] = e;
        ls += e;
    }
    ls = wredsum(ls);
    if ((tid & 63) == 0) red[4 + (tid >> 6)] = ls;
    __syncthreads();
    float invs = 1.f / (red[4] + red[5] + red[6] + red[7]);

    int kz = ((q >> 8) + 1) * 256;
    ushort_t* prow = P + ((size_t)b * S_ + q) * S_;
    for (int k = tid; k < kz; k += 256)
        prow[k] = (k < L) ? f2bf(srs[k] * invs) : (ushort_t)0;
}

// ---------------- sparse routing (adds PV K-split partial for q>=1024) ----------------
__global__ __launch_bounds__(256)
void routing_kernel(const float* __restrict__ attn, const float* __restrict__ attn2,
                    ushort_t* __restrict__ combined) {
    int wave = threadIdx.x >> 6, lane = threadIdx.x & 63;
    size_t row = (size_t)blockIdx.x * 4 + wave;
    const float4* a4 = (const float4*)(attn + row * H_);
    float4 x0 = a4[lane * 4 + 0], x1 = a4[lane * 4 + 1];
    float4 x2 = a4[lane * 4 + 2], x3 = a4[lane * 4 + 3];
    int q = (int)(row & 2047);
    if (q >= 1024) {
        size_t b = row >> 11;
        const float4* a2 = (const float4*)(attn2 + ((b * 1024 + (size_t)(q - 1024)) * H_));
        float4 y0 = a2[lane * 4 + 0], y1 = a2[lane * 4 + 1];
        float4 y2 = a2[lane * 4 + 2], y3 = a2[lane * 4 + 3];
        x0.x += y0.x; x0.y += y0.y; x0.z += y0.z; x0.w += y0.w;
        x1.x += y1.x; x1.y += y1.y; x1.z += y1.z; x1.w += y1.w;
        x2.x += y2.x; x2.y += y2.y; x2.z += y2.z; x2.w += y2.w;
        x3.x += y3.x; x3.y += y3.y; x3.z += y3.z; x3.w += y3.w;
    }
    float ss = x0.x * x0.x + x0.y * x0.y + x0.z * x0.z + x0.w * x0.w
             + x1.x * x1.x + x1.y * x1.y + x1.z * x1.z + x1.w * x1.w
             + x2.x * x2.x + x2.y * x2.y + x2.z * x2.z + x2.w * x2.w
             + x3.x * x3.x + x3.y * x3.y + x3.z * x3.z + x3.w * x3.w;
    float sc = sqrtf(ss);

    float v = sc, thr = 0.f, mx = 0.f;
#pragma unroll
    for (int i = 0; i < 16; i++) {
        float mm = wredmax(v);
        if (i == 0) mx = mm;
        thr = mm;
        if (v == mm) v = -1e30f;
    }
    float e = (sc >= thr) ? __expf(sc - mx) : 0.f;
    float se = wredsum(e);
    float w = e / se;

    const float xs[16] = {x0.x, x0.y, x0.z, x0.w, x1.x, x1.y, x1.z, x1.w,
                          x2.x, x2.y, x2.z, x2.w, x3.x, x3.y, x3.z, x3.w};
    union { ushort_t u[16]; uint4 q4[2]; } pk;
#pragma unroll
    for (int j = 0; j < 16; j++) pk.u[j] = f2bf(xs[j] * w);
    uint4* dst = (uint4*)(combined + row * H_ + lane * 16);
    dst[0] = pk.q4[0];
    dst[1] = pk.q4[1];
}

// ---------------- mean over S of combined ----------------
__global__ void cmean_part(const ushort_t* __restrict__ comb, float* __restrict__ part) {
    int d = blockIdx.x * 256 + threadIdx.x;
    int sc = blockIdx.y, b = blockIdx.z;
    const ushort_t* p = comb + ((size_t)b * S_ + sc * 128) * H_ + d;
    float s = 0.f;
    for (int i = 0; i < 128; i++) s += __uint_as_float((unsigned)p[(size_t)i * H_] << 16);
    part[((size_t)b * 16 + sc) * H_ + d] = s;
}

__global__ void cmean_final(const float* __restrict__ part, float* __restrict__ cm) {
    int idx = blockIdx.x * 256 + threadIdx.x;  // 0..8191
    int b = idx >> 10, d = idx & 1023;
    float s = 0.f;
#pragma unroll
    for (int c = 0; c < 16; c++) s += part[((size_t)b * 16 + c) * DIN_ + d];
    cm[idx] = s * (1.0f / 2048.0f);
}

// ---------------- x = cmean @ Wo^T + bo (fp32) ----------------
__global__ __launch_bounds__(256)
void xgemv(const float* __restrict__ cm, const float* __restrict__ Wo,
           const float* __restrict__ bo, float* __restrict__ x) {
    int wave = threadIdx.x >> 6, lane = threadIdx.x & 63;
    int i = blockIdx.x * 4 + wave;  // 0..1023
    const float4* wr4 = (const float4*)(Wo + (size_t)i * H_);
    float4 w[4];
#pragma unroll
    for (int c = 0; c < 4; c++) w[c] = wr4[c * 64 + lane];
    float accv[B_];
#pragma unroll
    for (int b = 0; b < B_; b++) {
        const float4* c4 = (const float4*)(cm + (size_t)b * H_);
        float s = 0.f;
#pragma unroll
        for (int c = 0; c < 4; c++) {
            float4 h = c4[c * 64 + lane];
            s += w[c].x * h.x + w[c].y * h.y + w[c].z * h.z + w[c].w * h.w;
        }
        accv[b] = wredsum(s);
    }
    if (lane == 0) {
        float bi = bo[i];
#pragma unroll
        for (int b = 0; b < B_; b++) x[(size_t)b * DIN_ + i] = accv[b] + bi;
    }
}

// ---------------- demopack decoder ----------------
__global__ __launch_bounds__(64)
void decode_hidden(const float* __restrict__ x, const float* __restrict__ codebook,
                   const int* __restrict__ instr, float* __restrict__ hidden) {
    int r = blockIdx.x;
    int lane = threadIdx.x;
    int idx = instr[r * 64 + lane];
    const float4* cw = (const float4*)(codebook + (size_t)idx * 16);
    float4 c0 = cw[0], c1 = cw[1], c2 = cw[2], c3 = cw[3];
    float acc[B_];
#pragma unroll
    for (int b = 0; b < B_; b++) {
        const float4* xb = (const float4*)(x + (size_t)b * DIN_ + lane * 16);
        float4 h0 = xb[0], h1 = xb[1], h2 = xb[2], h3 = xb[3];
        acc[b] = c0.x * h0.x + c0.y * h0.y + c0.z * h0.z + c0.w * h0.w
               + c1.x * h1.x + c1.y * h1.y + c1.z * h1.z + c1.w * h1.w
               + c2.x * h2.x + c2.y * h2.y + c2.z * h2.z + c2.w * h2.w
               + c3.x * h3.x + c3.y * h3.y + c3.z * h3.z + c3.w * h3.w;
    }
#pragma unroll
    for (int b = 0; b < B_; b++) acc[b] = wredsum(acc[b]);
    if (lane == 0) {
#pragma unroll
        for (int b = 0; b < B_; b++) hidden[(size_t)b * 1024 + r] = acc[b];
    }
}

// ---------------- LM head ----------------
__global__ __launch_bounds__(256)
void lm_head(const float* __restrict__ Wlm, const float* __restrict__ hidden,
             const float* __restrict__ blm, float* __restrict__ out) {
    int wave = threadIdx.x >> 6, lane = threadIdx.x & 63;
    for (int v = blockIdx.x * 4 + wave; v < V_; v += gridDim.x * 4) {
        const float4* wrow = (const float4*)(Wlm + (size_t)v * 1024);
        float acc[B_];
#pragma unroll
        for (int b = 0; b < B_; b++) acc[b] = 0.f;
#pragma unroll
        for (int rr = 0; rr < 4; rr++) {
            float4 wv = wrow[rr * 64 + lane];
#pragma unroll
            for (int b = 0; b < B_; b++) {
                float4 hv = ((const float4*)hidden)[b * 256 + rr * 64 + lane];
                acc[b] += wv.x * hv.x + wv.y * hv.y + wv.z * hv.z + wv.w * hv.w;
            }
        }
#pragma unroll
        for (int b = 0; b < B_; b++) acc[b] = wredsum(acc[b]);
        if (lane == 0) {
            float bl = blm[v];
#pragma unroll
            for (int b = 0; b < B_; b++) out[(size_t)b * V_ + v] = acc[b] + bl;
        }
    }
}

// ---------------- host launch ----------------
extern "C" void kernel_launch(void* const* d_in, const int* in_sizes, int n_in,
                              void* d_out, int out_size, void* d_ws, size_t ws_size,
                              hipStream_t stream) {
    const float* inputs = (const float*)d_in[0];
    const float* Wt  = (const float*)d_in[1];
    const float* bt  = (const float*)d_in[2];
    const float* Wq  = (const float*)d_in[3];
    const float* bq  = (const float*)d_in[4];
    const float* Wk  = (const float*)d_in[5];
    const float* bk  = (const float*)d_in[6];
    const float* Wv  = (const float*)d_in[7];
    const float* bv  = (const float*)d_in[8];
    const float* Wo  = (const float*)d_in[9];
    const float* bo  = (const float*)d_in[10];
    const float* codebook = (const float*)d_in[11];
    const int*   instructions = (const int*)d_in[12];
    const float* Wlm = (const float*)d_in[13];
    const float* blm = (const float*)d_in[14];
    float* out = (float*)d_out;

    (void)hipFuncSetAttribute(reinterpret_cast<const void*>(&gemm256<1, 0>),
                              hipFuncAttributeMaxDynamicSharedMemorySize, 131072);
    (void)hipFuncSetAttribute(reinterpret_cast<const void*>(&gemm256<0, 1>),
                              hipFuncAttributeMaxDynamicSharedMemorySize, 131072);
    (void)hipFuncSetAttribute(reinterpret_cast<const void*>(&gemm256<0, 2>),
                              hipFuncAttributeMaxDynamicSharedMemorySize, 131072);

    const size_t MB = 1024 * 1024;
    char* ws = (char*)d_ws;
    ushort_t* wqkv_bf = (ushort_t*)(ws + 0);             // 6 MB
    ushort_t* wtT_bf  = (ushort_t*)(ws + 6 * MB);        // 2 MB
    ushort_t* wcomb   = (ushort_t*)(ws + 8 * MB);        // 6 MB
    float* bcomb  = (float*)(ws + 14 * MB);              // 12 KB
    float* pbias  = (float*)(ws + 14 * MB + 64 * 1024);  // 8 KB
    float* cm     = (float*)(ws + 14 * MB + 128 * 1024); // 32 KB
    float* xbuf   = (float*)(ws + 14 * MB + 192 * 1024); // 32 KB
    float* hidden = (float*)(ws + 14 * MB + 256 * 1024); // 32 KB
    float* part   = (float*)(ws + 14 * MB + 512 * 1024); // 512 KB
    ushort_t* inbf   = (ushort_t*)(ws + 16 * MB);   // 32 MB  [16,48)   dead after QKV
    ushort_t* qkv    = (ushort_t*)(ws + 48 * MB);   // 96 MB  [48,144)  dead after scores+transpose
    ushort_t* vT     = (ushort_t*)(ws + 144 * MB);  // 32 MB  [144,176)
    float* scores    = (float*)(ws + 176 * MB);     // 128 MB [176,304) dead after softmax
    ushort_t* P      = (ushort_t*)(ws + 304 * MB);  // 64 MB  [304,368)
    float* attn      = (float*)(ws + 48 * MB);      // 64 MB  alias over inbf/qkv
    float* attn2     = (float*)(ws + 112 * MB);     // 32 MB  alias over qkv tail
    ushort_t* combined = (ushort_t*)(ws + 176 * MB);// 32 MB  alias over scores

    // 1) conversions + tables
    f2bf_vec<<<16384, 256, 0, stream>>>(inputs, inbf, 4194304);
    f2bf_w3<<<3072, 256, 0, stream>>>(Wq, Wk, Wv, wqkv_bf);
    transpose_wt<<<dim3(16, 16), 256, 0, stream>>>(Wt, wtT_bf);
    bcomb_kernel<<<768, 256, 0, stream>>>(Wq, Wk, Wv, bq, bk, bv, bt, bcomb);
    pos_bias_kernel<<<8, 256, 0, stream>>>(pbias);

    // 2) W_comb = Wqkv @ Wt  [3072,1024] bf16
    gemm_bt<1><<<dim3(8, 24), 256, 0, stream>>>(wqkv_bf, 1024, wtT_bf, 1024,
                                                wcomb, 1024, 1024, nullptr);

    // 3) qkv = inputs @ W_comb^T + b_comb  [16384,3072] bf16
    gemm256<1, 0><<<dim3(768, 1), 512, 131072, stream>>>(
        inbf, 0, 1024, wcomb, 0, 1024, qkv, 0, 3072, 1024, bcomb, 12, 768, nullptr);

    // 4) vT[b][h][s]
    transpose_v<<<dim3(32, 16, 8), 256, 0, stream>>>(qkv, vT);

    // 5) scores[b] = q @ k^T (packed causal tiles, 36 per batch) fp32
    gemm256<0, 1><<<dim3(36, 8), 512, 131072, stream>>>(
        qkv, (size_t)S_ * 3072, 3072, qkv + 1024, (size_t)S_ * 3072, 3072,
        scores, (size_t)S_ * S_, S_, 1024, nullptr, 36, 36, nullptr);

    // 6) softmax -> P bf16
    softmax_kernel<<<dim3(S_, B_), 256, 0, stream>>>(scores, P, pbias);

    // 7) attn[b] = P @ vT^T fp32, K-split balanced single dispatch
    gemm256<0, 2><<<dim3(48, 8), 512, 131072, stream>>>(
        P, (size_t)S_ * S_, S_, vT, (size_t)H_ * S_, S_,
        attn, (size_t)S_ * H_, H_, S_, nullptr, 0, 0, attn2 - (size_t)1024 * 1024);

    // 8) routing (attn + attn2 partial) -> combined bf16
    routing_kernel<<<4096, 256, 0, stream>>>(attn, attn2, combined);

    // 9) x = mean_s(combined) @ Wo^T + bo
    cmean_part<<<dim3(4, 16, 8), 256, 0, stream>>>(combined, part);
    cmean_final<<<32, 256, 0, stream>>>(part, cm);
    xgemv<<<256, 256, 0, stream>>>(cm, Wo, bo, xbuf);

    // 10) hidden = x @ W_dec^T
    decode_hidden<<<1024, 64, 0, stream>>>(xbuf, codebook, instructions, hidden);

    // 11) out = hidden @ W_lm^T + b_lm
    lm_head<<<2048, 256, 0, stream>>>(Wlm, hidden, blm, out);
}

// Round 9
// 451.543 us; speedup vs baseline: 1.1856x; 1.1856x over previous
//
#include <hip/hip_runtime.h>
#include <cstdint>
#include <cstddef>

#define B_   8
#define S_   2048
#define DIN_ 1024
#define H_   1024
#define V_   50257

typedef unsigned short ushort_t;
typedef __bf16 bf16x8 __attribute__((ext_vector_type(8)));
typedef float  f32x4  __attribute__((ext_vector_type(4)));

__device__ __forceinline__ ushort_t f2bf(float x) {
    unsigned u = __float_as_uint(x);
    u = (u + 0x7fffu + ((u >> 16) & 1u)) >> 16;
    return (ushort_t)u;
}

__device__ __forceinline__ void async16(const void* g, void* s) {
    __builtin_amdgcn_global_load_lds(
        (const __attribute__((address_space(1))) unsigned int*)g,
        (__attribute__((address_space(3))) unsigned int*)s, 16, 0, 0);
}

__device__ __forceinline__ float wredmax(float v) {
#pragma unroll
    for (int o = 32; o; o >>= 1) v = fmaxf(v, __shfl_xor(v, o));
    return v;
}
__device__ __forceinline__ float wredsum(float v) {
#pragma unroll
    for (int o = 32; o; o >>= 1) v += __shfl_xor(v, o);
    return v;
}

// ---------------- elementwise / setup ----------------
__global__ void f2bf_vec(const float* __restrict__ in, ushort_t* __restrict__ out, int n4) {
    int i = blockIdx.x * 256 + threadIdx.x;
    if (i >= n4) return;
    float4 f = ((const float4*)in)[i];
    ushort4 u;
    u.x = f2bf(f.x); u.y = f2bf(f.y); u.z = f2bf(f.z); u.w = f2bf(f.w);
    ((ushort4*)out)[i] = u;
}

// Wq|Wk|Wv (each 1024x1024 fp32) -> wqkv_bf (3*1048576 bf16)
__global__ void f2bf_w3(const float* __restrict__ Wq, const float* __restrict__ Wk,
                        const float* __restrict__ Wv, ushort_t* __restrict__ out) {
    int i = blockIdx.x * 256 + threadIdx.x;  // 0..786431 (float4 units)
    int w = i >> 18, off = i & 262143;
    const float* src = w == 0 ? Wq : (w == 1 ? Wk : Wv);
    float4 f = ((const float4*)src)[off];
    ushort4 u;
    u.x = f2bf(f.x); u.y = f2bf(f.y); u.z = f2bf(f.z); u.w = f2bf(f.w);
    ((ushort4*)(out + (size_t)w * 1048576))[off] = u;
}

__global__ void pos_bias_kernel(float* __restrict__ bias) {
    int k = blockIdx.x * 256 + threadIdx.x;
    if (k >= S_) return;
    float ang = 6.283185307179586f * (float)k / 1024.0f;
    float b = 0.f;
    b += sinf(1.f * ang) + cosf(1.f * ang);
    b += sinf(2.f * ang) + cosf(2.f * ang);
    b += sinf(4.f * ang) + cosf(4.f * ang);
    bias[k] = b;
}

// Wt[1024k][1024i] fp32 -> wtT[1024i][1024k] bf16
__global__ __launch_bounds__(256)
void transpose_wt(const float* __restrict__ Wt, ushort_t* __restrict__ wtT) {
    __shared__ float t[64][65];
    int k0 = blockIdx.x * 64, i0 = blockIdx.y * 64;
    int tx = threadIdx.x & 63, ty = threadIdx.x >> 6;
#pragma unroll
    for (int j = 0; j < 16; j++) {
        int k = ty * 16 + j;
        t[k][tx] = Wt[(size_t)(k0 + k) * DIN_ + i0 + tx];
    }
    __syncthreads();
#pragma unroll
    for (int j = 0; j < 16; j++) {
        int i = ty * 16 + j;
        wtT[(size_t)(i0 + i) * H_ + k0 + tx] = f2bf(t[tx][i]);
    }
}

// b_comb[j] = b{q,k,v}[j%1024] + dot(W{q,k,v}[j%1024], bt)
__global__ __launch_bounds__(256)
void bcomb_kernel(const float* __restrict__ Wq, const float* __restrict__ Wk,
                  const float* __restrict__ Wv, const float* __restrict__ bq,
                  const float* __restrict__ bk, const float* __restrict__ bv,
                  const float* __restrict__ bt, float* __restrict__ bcomb) {
    int wave = threadIdx.x >> 6, lane = threadIdx.x & 63;
    int j = blockIdx.x * 4 + wave;
    const float* W  = j < 1024 ? Wq : (j < 2048 ? Wk : Wv);
    const float* bb = j < 1024 ? bq : (j < 2048 ? bk : bv);
    int rowj = j & 1023;
    const float4* wr4 = (const float4*)(W + (size_t)rowj * 1024);
    const float4* bt4 = (const float4*)bt;
    float s = 0.f;
#pragma unroll
    for (int c = 0; c < 4; c++) {
        float4 w = wr4[c * 64 + lane];
        float4 b = bt4[c * 64 + lane];
        s += w.x * b.x + w.y * b.y + w.z * b.z + w.w * b.w;
    }
    s = wredsum(s);
    if (lane == 0) bcomb[j] = s + bb[rowj];
}

// ---------------- 128^2 m97-structure GEMM — small GEMMs ----------------
template <int OUT_BF16>
__global__ __launch_bounds__(256)
void gemm_bt(const ushort_t* __restrict__ A, int lda,
             const ushort_t* __restrict__ Bt, int ldb,
             void* __restrict__ Cv, int ldc, int K, const float* __restrict__ bias) {
    int bn = blockIdx.x, bm = blockIdx.y;
    __shared__ ushort_t As[128 * 32];
    __shared__ ushort_t Bs[128 * 32];
    int tid = threadIdx.x, wave = tid >> 6, lane = tid & 63;
    int wr = wave >> 1, wc = wave & 1;
    int nkt = K >> 5;
    int srow = lane >> 2, scol = (lane & 3) * 8;
    size_t arow0 = (size_t)bm * 128, brow0 = (size_t)bn * 128;
    f32x4 acc[4][4];
#pragma unroll
    for (int m = 0; m < 4; m++)
#pragma unroll
        for (int n = 0; n < 4; n++) acc[m][n] = f32x4{0.f, 0.f, 0.f, 0.f};
    for (int kt = 0; kt < nkt; ++kt) {
        int k0 = kt * 32;
#pragma unroll
        for (int i = 0; i < 2; i++) {
            int reg = wave * 2 + i;
            int row = reg * 16 + srow;
            async16(A + (arow0 + row) * (size_t)lda + k0 + scol, (ushort_t*)As + reg * 512);
            async16(Bt + (brow0 + row) * (size_t)ldb + k0 + scol, (ushort_t*)Bs + reg * 512);
        }
        __syncthreads();
        bf16x8 af[4], bfr[4];
#pragma unroll
        for (int m = 0; m < 4; m++)
            af[m] = *(const bf16x8*)&As[(wr * 64 + m * 16 + (lane & 15)) * 32 + (lane >> 4) * 8];
#pragma unroll
        for (int n = 0; n < 4; n++)
            bfr[n] = *(const bf16x8*)&Bs[(wc * 64 + n * 16 + (lane & 15)) * 32 + (lane >> 4) * 8];
#pragma unroll
        for (int m = 0; m < 4; m++)
#pragma unroll
            for (int n = 0; n < 4; n++)
                acc[m][n] = __builtin_amdgcn_mfma_f32_16x16x32_bf16(af[m], bfr[n], acc[m][n], 0, 0, 0);
        __syncthreads();
    }
    int rl = (lane >> 4) * 4, cl = lane & 15;
#pragma unroll
    for (int m = 0; m < 4; m++)
#pragma unroll
        for (int n = 0; n < 4; n++) {
            int col = bn * 128 + wc * 64 + n * 16 + cl;
            float badd = bias ? bias[col] : 0.f;
#pragma unroll
            for (int r = 0; r < 4; r++) {
                int row = bm * 128 + wr * 64 + m * 16 + rl + r;
                float v = acc[m][n][r] + badd;
                size_t off = (size_t)row * ldc + col;
                if (OUT_BF16) ((ushort_t*)Cv)[off] = f2bf(v);
                else          ((float*)Cv)[off] = v;
            }
        }
}

// ---------------- 256^2 4-phase pipelined GEMM (r4 schedule + bf23 moved to p1) ----------------
// MODE 0: plain (QKV). MODE 1: causal-packed lower-triangle tiles (scores).
// MODE 2: PV K-split (A-set x<32: K capped 1024 -> attn; B-set x>=32: K in
//         [1024,(bm+1)*256) descending-K order -> Cv2(attn2), nkt<=16 everywhere).
// Schedule per K-tile (BK=64, 2 LDS buffers, 128KB dynamic), 4 barriers/tile:
//   p0: read af47(t)(8)             | Q0=A03xB01 | lgkm0 | BARRIER
//   p1: read bf23(t)(4)             | Q1=A47xB01 | BARRIER
//   p2: stage A(t+2,h0)             | Q2=A03xB23 | vmcnt(2) | BARRIER
//   p3: read af03,bf01(t+1)(12) | stage A(t+2,h1),B(t+2,h0),B(t+2,h1) | Q3=A47xB23 | BARRIER
// Hazards: af47 drained by p0 lgkm0 (overwritten @p3 STG_A h1, 3 barriers later).
// bf23 read p1, implicit-wait before Q2 (p2) -> returned before p2-end barrier,
// STG_B(t+2)@p3 is after -> safe. t+1 reads follow vmcnt(2)->barrier (r3 lesson).
// Swizzle: 16B-slot ^= (row&7) -> measured 0 conflicts; inverse on global src.
template <int OUT_BF16, int MODE>
__global__ __launch_bounds__(512, 2)
void gemm256(const ushort_t* __restrict__ A, size_t sAb, int lda,
             const ushort_t* __restrict__ Bt, size_t sBb, int ldb,
             void* __restrict__ Cv, size_t sCb, int ldc,
             int K, const float* __restrict__ bias, int nbn, int nwg,
             float* __restrict__ Cv2) {
    extern __shared__ char lds[];
    int bz = blockIdx.y;
    int bm, bn, koff = 0, nkt;
    void* Cuse = Cv;
    size_t sCuse = sCb;
    if (MODE == 2) {
        int x = blockIdx.x;  // 0..47, no swizzle
        if (x < 32) {
            bm = x >> 2; bn = x & 3;
            int km = (bm + 1) * 256; if (km > 1024) km = 1024;
            nkt = km >> 6;
        } else {
            int j = x - 32;
            bm = 7 - (j >> 2); bn = j & 3;           // descending-K dispatch order
            koff = 1024;
            nkt = ((bm + 1) * 256 - 1024) >> 6;
            Cuse = Cv2;                               // pre-offset by -1024*ldc rows
            sCuse = (size_t)1024 * 1024;
        }
    } else {
        int orig = blockIdx.x;
        int qq = nwg >> 3, rr8 = nwg & 7;
        int xcd = orig & 7, bidx = orig >> 3;
        int wgid = (xcd < rr8 ? xcd * (qq + 1) : rr8 * (qq + 1) + (xcd - rr8) * qq) + bidx;
        if (MODE == 1) {  // lower-triangle pack: wgid in [0,36)
            int w = wgid;
            bm = 0;
            while ((bm + 1) * (bm + 2) / 2 <= w) bm++;
            bn = w - bm * (bm + 1) / 2;
        } else {
            bm = wgid / nbn; bn = wgid - bm * nbn;
        }
        nkt = K >> 6;
    }

    const ushort_t* Ab = A + (size_t)bz * sAb;
    const ushort_t* Bb = Bt + (size_t)bz * sBb;
    int tid = threadIdx.x, wave = tid >> 6, lane = tid & 63;
    int wr = wave >> 2, wc = wave & 3;

    // ---- staging addressing (inverse-swizzled global source) ----
    int srow = wave * 8 + (lane >> 3);            // 0..63
    int sswz = ((lane & 7) ^ (lane >> 3)) * 8;    // k-elem offset
    const ushort_t* Ag = Ab + ((size_t)bm * 256 + srow) * (size_t)lda + sswz + koff;
    const ushort_t* Bg = Bb + ((size_t)bn * 256 + srow) * (size_t)ldb + sswz + koff;
    int sdst = wave * 1024;

    // ---- frag read addressing (swizzled) ----
    int fr = lane & 15, g = lane >> 4;
    int kx = (fr >> 2) & 1;
    int gsw = (g ^ (fr & 3)) * 16;
    int aoff = wr * 16384 + fr * 128 + gsw;                    // + bufo + mf*2048 + ksel
    int boff = 32768 + (wc >> 1) * 16384 + ((wc & 1) * 64 + fr) * 128 + gsw;
    int ks0 = kx << 6, ks1 = (kx ^ 1) << 6;                    // LDS slot for kk=0/1

    f32x4 acc[8][4];
#pragma unroll
    for (int m = 0; m < 8; m++)
#pragma unroll
        for (int n = 0; n < 4; n++) acc[m][n] = f32x4{0.f, 0.f, 0.f, 0.f};

#define STG_A(t, h, bo)                                                        \
    do {                                                                       \
        async16(Ag + (size_t)((h) * 128) * lda + (t) * 64,                     \
                lds + (bo) + (h) * 16384 + sdst);                              \
        async16(Ag + (size_t)((h) * 128 + 64) * lda + (t) * 64,                \
                lds + (bo) + (h) * 16384 + 8192 + sdst);                       \
    } while (0)
#define STG_B(t, h, bo)                                                        \
    do {                                                                       \
        async16(Bg + (size_t)((h) * 128) * ldb + (t) * 64,                     \
                lds + (bo) + 32768 + (h) * 16384 + sdst);                      \
        async16(Bg + (size_t)((h) * 128 + 64) * ldb + (t) * 64,                \
                lds + (bo) + 32768 + (h) * 16384 + 8192 + sdst);               \
    } while (0)

    // ---- prologue: tile0 -> buf0 (8 loads), tile1 -> buf1 (8 loads) ----
    STG_A(0, 0, 0); STG_A(0, 1, 0); STG_B(0, 0, 0); STG_B(0, 1, 0);
    STG_A(1, 0, 65536); STG_A(1, 1, 65536); STG_B(1, 0, 65536); STG_B(1, 1, 65536);
    asm volatile("s_waitcnt vmcnt(8)" ::: "memory");  // tile0 landed; tile1 in flight
    __builtin_amdgcn_sched_barrier(0);
    __builtin_amdgcn_s_barrier();
    __builtin_amdgcn_sched_barrier(0);

    bf16x8 af03[4][2], af47[4][2], bf01[2][2], bf23[2][2];
#pragma unroll
    for (int mf = 0; mf < 4; mf++) {
        af03[mf][0] = *(const bf16x8*)(lds + aoff + mf * 2048 + ks0);
        af03[mf][1] = *(const bf16x8*)(lds + aoff + mf * 2048 + ks1);
    }
#pragma unroll
    for (int nf = 0; nf < 2; nf++) {
        bf01[nf][0] = *(const bf16x8*)(lds + boff + nf * 2048 + ks0);
        bf01[nf][1] = *(const bf16x8*)(lds + boff + nf * 2048 + ks1);
    }

    int bufo = 0;
    for (int t = 0; t < nkt; ++t, bufo ^= 65536) {
        int nb = bufo ^ 65536;
        // ======== phase 0: read af47(t)(8); Q0 = A03 x B01 ========
#pragma unroll
        for (int mf = 0; mf < 4; mf++) {
            af47[mf][0] = *(const bf16x8*)(lds + bufo + aoff + (mf + 4) * 2048 + ks0);
            af47[mf][1] = *(const bf16x8*)(lds + bufo + aoff + (mf + 4) * 2048 + ks1);
        }
        __builtin_amdgcn_s_setprio(1);
#pragma unroll
        for (int mf = 0; mf < 4; mf++)
#pragma unroll
            for (int nf = 0; nf < 2; nf++) {
                acc[mf][nf] = __builtin_amdgcn_mfma_f32_16x16x32_bf16(af03[mf][0], bf01[nf][0], acc[mf][nf], 0, 0, 0);
                acc[mf][nf] = __builtin_amdgcn_mfma_f32_16x16x32_bf16(af03[mf][1], bf01[nf][1], acc[mf][nf], 0, 0, 0);
            }
        __builtin_amdgcn_s_setprio(0);
        __builtin_amdgcn_sched_barrier(0);
        asm volatile("s_waitcnt lgkmcnt(0)" ::: "memory");
        __builtin_amdgcn_sched_barrier(0);
        __builtin_amdgcn_s_barrier();
        __builtin_amdgcn_sched_barrier(0);

        // ======== phase 1: read bf23(t)(4); Q1 = A47 x B01 ========
#pragma unroll
        for (int nf = 0; nf < 2; nf++) {
            bf23[nf][0] = *(const bf16x8*)(lds + bufo + boff + (nf + 2) * 2048 + ks0);
            bf23[nf][1] = *(const bf16x8*)(lds + bufo + boff + (nf + 2) * 2048 + ks1);
        }
        __builtin_amdgcn_s_setprio(1);
#pragma unroll
        for (int mf = 0; mf < 4; mf++)
#pragma unroll
            for (int nf = 0; nf < 2; nf++) {
                acc[mf + 4][nf] = __builtin_amdgcn_mfma_f32_16x16x32_bf16(af47[mf][0], bf01[nf][0], acc[mf + 4][nf], 0, 0, 0);
                acc[mf + 4][nf] = __builtin_amdgcn_mfma_f32_16x16x32_bf16(af47[mf][1], bf01[nf][1], acc[mf + 4][nf], 0, 0, 0);
            }
        __builtin_amdgcn_s_setprio(0);
        __builtin_amdgcn_sched_barrier(0);
        __builtin_amdgcn_s_barrier();
        __builtin_amdgcn_sched_barrier(0);

        // ======== phase 2: stage A(t+2,h0); Q2 = A03 x B23; vmcnt ========
        if (t + 2 < nkt) STG_A(t + 2, 0, bufo);
        __builtin_amdgcn_s_setprio(1);
#pragma unroll
        for (int mf = 0; mf < 4; mf++)
#pragma unroll
            for (int nf = 0; nf < 2; nf++) {
                acc[mf][nf + 2] = __builtin_amdgcn_mfma_f32_16x16x32_bf16(af03[mf][0], bf23[nf][0], acc[mf][nf + 2], 0, 0, 0);
                acc[mf][nf + 2] = __builtin_amdgcn_mfma_f32_16x16x32_bf16(af03[mf][1], bf23[nf][1], acc[mf][nf + 2], 0, 0, 0);
            }
        __builtin_amdgcn_s_setprio(0);
        __builtin_amdgcn_sched_barrier(0);
        if (t + 1 < nkt) {
            if (t + 2 < nkt) { asm volatile("s_waitcnt vmcnt(2)" ::: "memory"); }
            else             { asm volatile("s_waitcnt vmcnt(0)" ::: "memory"); }
        }
        __builtin_amdgcn_s_barrier();   // propagates "tile t+1 landed" to all waves
        __builtin_amdgcn_sched_barrier(0);

        // ======== phase 3: read af03/bf01(t+1); stage A(t+2,h1),B(t+2); Q3 ========
        if (t + 1 < nkt) {
#pragma unroll
            for (int mf = 0; mf < 4; mf++) {
                af03[mf][0] = *(const bf16x8*)(lds + nb + aoff + mf * 2048 + ks0);
                af03[mf][1] = *(const bf16x8*)(lds + nb + aoff + mf * 2048 + ks1);
            }
#pragma unroll
            for (int nf = 0; nf < 2; nf++) {
                bf01[nf][0] = *(const bf16x8*)(lds + nb + boff + nf * 2048 + ks0);
                bf01[nf][1] = *(const bf16x8*)(lds + nb + boff + nf * 2048 + ks1);
            }
        }
        if (t + 2 < nkt) { STG_A(t + 2, 1, bufo); STG_B(t + 2, 0, bufo); STG_B(t + 2, 1, bufo); }
        __builtin_amdgcn_s_setprio(1);
#pragma unroll
        for (int mf = 0; mf < 4; mf++)
#pragma unroll
            for (int nf = 0; nf < 2; nf++) {
                acc[mf + 4][nf + 2] = __builtin_amdgcn_mfma_f32_16x16x32_bf16(af47[mf][0], bf23[nf][0], acc[mf + 4][nf + 2], 0, 0, 0);
                acc[mf + 4][nf + 2] = __builtin_amdgcn_mfma_f32_16x16x32_bf16(af47[mf][1], bf23[nf][1], acc[mf + 4][nf + 2], 0, 0, 0);
            }
        __builtin_amdgcn_s_setprio(0);
        __builtin_amdgcn_sched_barrier(0);
        __builtin_amdgcn_s_barrier();
        __builtin_amdgcn_sched_barrier(0);
    }
#undef STG_A
#undef STG_B

    int rl = (lane >> 4) * 4, cl = lane & 15;
#pragma unroll
    for (int mf = 0; mf < 8; mf++)
#pragma unroll
        for (int nf = 0; nf < 4; nf++) {
            int col = bn * 256 + wc * 64 + nf * 16 + cl;
            float badd = bias ? bias[col] : 0.f;
#pragma unroll
            for (int r = 0; r < 4; r++) {
                int row = bm * 256 + wr * 128 + mf * 16 + rl + r;
                float v = acc[mf][nf][r] + badd;
                size_t off = (size_t)bz * sCuse + (size_t)row * ldc + col;
                if (OUT_BF16) ((ushort_t*)Cuse)[off] = f2bf(v);
                else          ((float*)Cuse)[off] = v;
            }
        }
}

// ---------------- transpose V: qkv[b][s][2048+h] -> vT[b][h][s] ----------------
__global__ __launch_bounds__(256)
void transpose_v(const ushort_t* __restrict__ qkv, ushort_t* __restrict__ vT) {
    __shared__ ushort_t t[64][66];
    int b = blockIdx.z;
    int s0 = blockIdx.x * 64, h0 = blockIdx.y * 64;
    int tx = threadIdx.x & 63, ty = threadIdx.x >> 6;
#pragma unroll
    for (int i = 0; i < 16; i++) {
        int s = ty * 16 + i;
        t[s][tx] = qkv[((size_t)b * S_ + s0 + s) * 3072 + 2048 + h0 + tx];
    }
    __syncthreads();
#pragma unroll
    for (int i = 0; i < 16; i++) {
        int h = ty * 16 + i;
        vT[((size_t)b * H_ + h0 + h) * S_ + s0 + tx] = t[tx][h];
    }
}

// ---------------- softmax rows (vectorized, register-resident) ----------------
__global__ __launch_bounds__(256)
void softmax_kernel(const float* __restrict__ scores, ushort_t* __restrict__ P,
                    const float* __restrict__ bias) {
    __shared__ float red[8];
    int q = blockIdx.x, b = blockIdx.y;
    int L = q + 1;
    int tid = threadIdx.x;
    const float4* srow4 = (const float4*)(scores + ((size_t)b * S_ + q) * S_);
    const float4* bias4 = (const float4*)bias;
    const float scale = 0.03125f;  // 1/sqrt(1024)
    int kz = ((q >> 8) + 1) * 256;  // PV reads only k < kz for this row

    int k00 = tid * 4, k01 = 1024 + tid * 4;
    float4 v0 = {0.f, 0.f, 0.f, 0.f}, v1 = {0.f, 0.f, 0.f, 0.f};
    float lm = -3e38f;
    if (k00 < kz) {
        float4 s4 = srow4[tid];
        float4 b4 = bias4[tid];
        v0.x = (k00 + 0 < L) ? s4.x * scale + b4.x : -3e38f;
        v0.y = (k00 + 1 < L) ? s4.y * scale + b4.y : -3e38f;
        v0.z = (k00 + 2 < L) ? s4.z * scale + b4.z : -3e38f;
        v0.w = (k00 + 3 < L) ? s4.w * scale + b4.w : -3e38f;
        lm = fmaxf(fmaxf(v0.x, v0.y), fmaxf(v0.z, v0.w));
    }
    if (k01 < kz) {
        float4 s4 = srow4[256 + tid];
        float4 b4 = bias4[256 + tid];
        v1.x = (k01 + 0 < L) ? s4.x * scale + b4.x : -3e38f;
        v1.y = (k01 + 1 < L) ? s4.y * scale + b4.y : -3e38f;
        v1.z = (k01 + 2 < L) ? s4.z * scale + b4.z : -3e38f;
        v1.w = (k01 + 3 < L) ? s4.w * scale + b4.w : -3e38f;
        lm = fmaxf(lm, fmaxf(fmaxf(v1.x, v1.y), fmaxf(v1.z, v1.w)));
    }
    lm = wredmax(lm);
    if ((tid & 63) == 0) red[tid >> 6] = lm;
    __syncthreads();
    float m = fmaxf(fmaxf(red[0], red[1]), fmaxf(red[2], red[3]));

    float ls = 0.f;
    if (k00 < kz) {
        v0.x = __expf(v0.x - m); v0.y = __expf(v0.y - m);
        v0.z = __expf(v0.z - m); v0.w = __expf(v0.w - m);
        ls += v0.x + v0.y + v0.z + v0.w;
    }
    if (k01 < kz) {
        v1.x = __expf(v1.x - m); v1.y = __expf(v1.y - m);
        v1.z = __expf(v1.z - m); v1.w = __expf(v1.w - m);
        ls += v1.x + v1.y + v1.z + v1.w;
    }
    ls = wredsum(ls);
    if ((tid & 63) == 0) red[4 + (tid >> 6)] = ls;
    __syncthreads();
    float invs = 1.f / (red[4] + red[5] + red[6] + red[7]);

    ushort_t* prow = P + ((size_t)b * S_ + q) * S_;
    if (k00 < kz) {
        ushort4 o;
        o.x = f2bf(v0.x * invs); o.y = f2bf(v0.y * invs);
        o.z = f2bf(v0.z * invs); o.w = f2bf(v0.w * invs);
        ((ushort4*)prow)[tid] = o;   // masked lanes hold exp(-inf)=0 -> writes 0
    }
    if (k01 < kz) {
        ushort4 o;
        o.x = f2bf(v1.x * invs); o.y = f2bf(v1.y * invs);
        o.z = f2bf(v1.z * invs); o.w = f2bf(v1.w * invs);
        ((ushort4*)prow)[256 + tid] = o;
    }
}

// ---------------- sparse routing (adds PV K-split partial for q>=1024) ----------------
__global__ __launch_bounds__(256)
void routing_kernel(const float* __restrict__ attn, const float* __restrict__ attn2,
                    ushort_t* __restrict__ combined) {
    int wave = threadIdx.x >> 6, lane = threadIdx.x & 63;
    size_t row = (size_t)blockIdx.x * 4 + wave;
    const float4* a4 = (const float4*)(attn + row * H_);
    float4 x0 = a4[lane * 4 + 0], x1 = a4[lane * 4 + 1];
    float4 x2 = a4[lane * 4 + 2], x3 = a4[lane * 4 + 3];
    int q = (int)(row & 2047);
    if (q >= 1024) {
        size_t b = row >> 11;
        const float4* a2 = (const float4*)(attn2 + ((b * 1024 + (size_t)(q - 1024)) * H_));
        float4 y0 = a2[lane * 4 + 0], y1 = a2[lane * 4 + 1];
        float4 y2 = a2[lane * 4 + 2], y3 = a2[lane * 4 + 3];
        x0.x += y0.x; x0.y += y0.y; x0.z += y0.z; x0.w += y0.w;
        x1.x += y1.x; x1.y += y1.y; x1.z += y1.z; x1.w += y1.w;
        x2.x += y2.x; x2.y += y2.y; x2.z += y2.z; x2.w += y2.w;
        x3.x += y3.x; x3.y += y3.y; x3.z += y3.z; x3.w += y3.w;
    }
    float ss = x0.x * x0.x + x0.y * x0.y + x0.z * x0.z + x0.w * x0.w
             + x1.x * x1.x + x1.y * x1.y + x1.z * x1.z + x1.w * x1.w
             + x2.x * x2.x + x2.y * x2.y + x2.z * x2.z + x2.w * x2.w
             + x3.x * x3.x + x3.y * x3.y + x3.z * x3.z + x3.w * x3.w;
    float sc = sqrtf(ss);

    float v = sc, thr = 0.f, mx = 0.f;
#pragma unroll
    for (int i = 0; i < 16; i++) {
        float mm = wredmax(v);
        if (i == 0) mx = mm;
        thr = mm;
        if (v == mm) v = -1e30f;
    }
    float e = (sc >= thr) ? __expf(sc - mx) : 0.f;
    float se = wredsum(e);
    float w = e / se;

    const float xs[16] = {x0.x, x0.y, x0.z, x0.w, x1.x, x1.y, x1.z, x1.w,
                          x2.x, x2.y, x2.z, x2.w, x3.x, x3.y, x3.z, x3.w};
    union { ushort_t u[16]; uint4 q4[2]; } pk;
#pragma unroll
    for (int j = 0; j < 16; j++) pk.u[j] = f2bf(xs[j] * w);
    uint4* dst = (uint4*)(combined + row * H_ + lane * 16);
    dst[0] = pk.q4[0];
    dst[1] = pk.q4[1];
}

// ---------------- mean over S of combined ----------------
__global__ void cmean_part(const ushort_t* __restrict__ comb, float* __restrict__ part) {
    int d = blockIdx.x * 256 + threadIdx.x;
    int sc = blockIdx.y, b = blockIdx.z;
    const ushort_t* p = comb + ((size_t)b * S_ + sc * 128) * H_ + d;
    float s = 0.f;
    for (int i = 0; i < 128; i++) s += __uint_as_float((unsigned)p[(size_t)i * H_] << 16);
    part[((size_t)b * 16 + sc) * H_ + d] = s;
}

__global__ void cmean_final(const float* __restrict__ part, float* __restrict__ cm) {
    int idx = blockIdx.x * 256 + threadIdx.x;  // 0..8191
    int b = idx >> 10, d = idx & 1023;
    float s = 0.f;
#pragma unroll
    for (int c = 0; c < 16; c++) s += part[((size_t)b * 16 + c) * DIN_ + d];
    cm[idx] = s * (1.0f / 2048.0f);
}

// ---------------- x = cmean @ Wo^T + bo (fp32) ----------------
__global__ __launch_bounds__(256)
void xgemv(const float* __restrict__ cm, const float* __restrict__ Wo,
           const float* __restrict__ bo, float* __restrict__ x) {
    int wave = threadIdx.x >> 6, lane = threadIdx.x & 63;
    int i = blockIdx.x * 4 + wave;  // 0..1023
    const float4* wr4 = (const float4*)(Wo + (size_t)i * H_);
    float4 w[4];
#pragma unroll
    for (int c = 0; c < 4; c++) w[c] = wr4[c * 64 + lane];
    float accv[B_];
#pragma unroll
    for (int b = 0; b < B_; b++) {
        const float4* c4 = (const float4*)(cm + (size_t)b * H_);
        float s = 0.f;
#pragma unroll
        for (int c = 0; c < 4; c++) {
            float4 h = c4[c * 64 + lane];
            s += w[c].x * h.x + w[c].y * h.y + w[c].z * h.z + w[c].w * h.w;
        }
        accv[b] = wredsum(s);
    }
    if (lane == 0) {
        float bi = bo[i];
#pragma unroll
        for (int b = 0; b < B_; b++) x[(size_t)b * DIN_ + i] = accv[b] + bi;
    }
}

// ---------------- demopack decoder ----------------
__global__ __launch_bounds__(64)
void decode_hidden(const float* __restrict__ x, const float* __restrict__ codebook,
                   const int* __restrict__ instr, float* __restrict__ hidden) {
    int r = blockIdx.x;
    int lane = threadIdx.x;
    int idx = instr[r * 64 + lane];
    const float4* cw = (const float4*)(codebook + (size_t)idx * 16);
    float4 c0 = cw[0], c1 = cw[1], c2 = cw[2], c3 = cw[3];
    float acc[B_];
#pragma unroll
    for (int b = 0; b < B_; b++) {
        const float4* xb = (const float4*)(x + (size_t)b * DIN_ + lane * 16);
        float4 h0 = xb[0], h1 = xb[1], h2 = xb[2], h3 = xb[3];
        acc[b] = c0.x * h0.x + c0.y * h0.y + c0.z * h0.z + c0.w * h0.w
               + c1.x * h1.x + c1.y * h1.y + c1.z * h1.z + c1.w * h1.w
               + c2.x * h2.x + c2.y * h2.y + c2.z * h2.z + c2.w * h2.w
               + c3.x * h3.x + c3.y * h3.y + c3.z * h3.z + c3.w * h3.w;
    }
#pragma unroll
    for (int b = 0; b < B_; b++) acc[b] = wredsum(acc[b]);
    if (lane == 0) {
#pragma unroll
        for (int b = 0; b < B_; b++) hidden[(size_t)b * 1024 + r] = acc[b];
    }
}

// ---------------- LM head ----------------
__global__ __launch_bounds__(256)
void lm_head(const float* __restrict__ Wlm, const float* __restrict__ hidden,
             const float* __restrict__ blm, float* __restrict__ out) {
    int wave = threadIdx.x >> 6, lane = threadIdx.x & 63;
    for (int v = blockIdx.x * 4 + wave; v < V_; v += gridDim.x * 4) {
        const float4* wrow = (const float4*)(Wlm + (size_t)v * 1024);
        float acc[B_];
#pragma unroll
        for (int b = 0; b < B_; b++) acc[b] = 0.f;
#pragma unroll
        for (int rr = 0; rr < 4; rr++) {
            float4 wv = wrow[rr * 64 + lane];
#pragma unroll
            for (int b = 0; b < B_; b++) {
                float4 hv = ((const float4*)hidden)[b * 256 + rr * 64 + lane];
                acc[b] += wv.x * hv.x + wv.y * hv.y + wv.z * hv.z + wv.w * hv.w;
            }
        }
#pragma unroll
        for (int b = 0; b < B_; b++) acc[b] = wredsum(acc[b]);
        if (lane == 0) {
            float bl = blm[v];
#pragma unroll
            for (int b = 0; b < B_; b++) out[(size_t)b * V_ + v] = acc[b] + bl;
        }
    }
}

// ---------------- host launch ----------------
extern "C" void kernel_launch(void* const* d_in, const int* in_sizes, int n_in,
                              void* d_out, int out_size, void* d_ws, size_t ws_size,
                              hipStream_t stream) {
    const float* inputs = (const float*)d_in[0];
    const float* Wt  = (const float*)d_in[1];
    const float* bt  = (const float*)d_in[2];
    const float* Wq  = (const float*)d_in[3];
    const float* bq  = (const float*)d_in[4];
    const float* Wk  = (const float*)d_in[5];
    const float* bk  = (const float*)d_in[6];
    const float* Wv  = (const float*)d_in[7];
    const float* bv  = (const float*)d_in[8];
    const float* Wo  = (const float*)d_in[9];
    const float* bo  = (const float*)d_in[10];
    const float* codebook = (const float*)d_in[11];
    const int*   instructions = (const int*)d_in[12];
    const float* Wlm = (const float*)d_in[13];
    const float* blm = (const float*)d_in[14];
    float* out = (float*)d_out;

    (void)hipFuncSetAttribute(reinterpret_cast<const void*>(&gemm256<1, 0>),
                              hipFuncAttributeMaxDynamicSharedMemorySize, 131072);
    (void)hipFuncSetAttribute(reinterpret_cast<const void*>(&gemm256<0, 1>),
                              hipFuncAttributeMaxDynamicSharedMemorySize, 131072);
    (void)hipFuncSetAttribute(reinterpret_cast<const void*>(&gemm256<0, 2>),
                              hipFuncAttributeMaxDynamicSharedMemorySize, 131072);

    const size_t MB = 1024 * 1024;
    char* ws = (char*)d_ws;
    ushort_t* wqkv_bf = (ushort_t*)(ws + 0);             // 6 MB
    ushort_t* wtT_bf  = (ushort_t*)(ws + 6 * MB);        // 2 MB
    ushort_t* wcomb   = (ushort_t*)(ws + 8 * MB);        // 6 MB
    float* bcomb  = (float*)(ws + 14 * MB);              // 12 KB
    float* pbias  = (float*)(ws + 14 * MB + 64 * 1024);  // 8 KB
    float* cm     = (float*)(ws + 14 * MB + 128 * 1024); // 32 KB
    float* xbuf   = (float*)(ws + 14 * MB + 192 * 1024); // 32 KB
    float* hidden = (float*)(ws + 14 * MB + 256 * 1024); // 32 KB
    float* part   = (float*)(ws + 14 * MB + 512 * 1024); // 512 KB
    ushort_t* inbf   = (ushort_t*)(ws + 16 * MB);   // 32 MB  [16,48)   dead after QKV
    ushort_t* qkv    = (ushort_t*)(ws + 48 * MB);   // 96 MB  [48,144)  dead after scores+transpose
    ushort_t* vT     = (ushort_t*)(ws + 144 * MB);  // 32 MB  [144,176)
    float* scores    = (float*)(ws + 176 * MB);     // 128 MB [176,304) dead after softmax
    ushort_t* P      = (ushort_t*)(ws + 304 * MB);  // 64 MB  [304,368)
    float* attn      = (float*)(ws + 48 * MB);      // 64 MB  alias over inbf/qkv
    float* attn2     = (float*)(ws + 112 * MB);     // 32 MB  alias over qkv tail
    ushort_t* combined = (ushort_t*)(ws + 176 * MB);// 32 MB  alias over scores

    // 1) conversions + tables
    f2bf_vec<<<16384, 256, 0, stream>>>(inputs, inbf, 4194304);
    f2bf_w3<<<3072, 256, 0, stream>>>(Wq, Wk, Wv, wqkv_bf);
    transpose_wt<<<dim3(16, 16), 256, 0, stream>>>(Wt, wtT_bf);
    bcomb_kernel<<<768, 256, 0, stream>>>(Wq, Wk, Wv, bq, bk, bv, bt, bcomb);
    pos_bias_kernel<<<8, 256, 0, stream>>>(pbias);

    // 2) W_comb = Wqkv @ Wt  [3072,1024] bf16
    gemm_bt<1><<<dim3(8, 24), 256, 0, stream>>>(wqkv_bf, 1024, wtT_bf, 1024,
                                                wcomb, 1024, 1024, nullptr);

    // 3) qkv = inputs @ W_comb^T + b_comb  [16384,3072] bf16
    gemm256<1, 0><<<dim3(768, 1), 512, 131072, stream>>>(
        inbf, 0, 1024, wcomb, 0, 1024, qkv, 0, 3072, 1024, bcomb, 12, 768, nullptr);

    // 4) vT[b][h][s]
    transpose_v<<<dim3(32, 16, 8), 256, 0, stream>>>(qkv, vT);

    // 5) scores[b] = q @ k^T (packed causal tiles, 36 per batch) fp32
    gemm256<0, 1><<<dim3(36, 8), 512, 131072, stream>>>(
        qkv, (size_t)S_ * 3072, 3072, qkv + 1024, (size_t)S_ * 3072, 3072,
        scores, (size_t)S_ * S_, S_, 1024, nullptr, 36, 36, nullptr);

    // 6) softmax -> P bf16
    softmax_kernel<<<dim3(S_, B_), 256, 0, stream>>>(scores, P, pbias);

    // 7) attn[b] = P @ vT^T fp32, K-split balanced single dispatch
    gemm256<0, 2><<<dim3(48, 8), 512, 131072, stream>>>(
        P, (size_t)S_ * S_, S_, vT, (size_t)H_ * S_, S_,
        attn, (size_t)S_ * H_, H_, S_, nullptr, 0, 0, attn2 - (size_t)1024 * 1024);

    // 8) routing (attn + attn2 partial) -> combined bf16
    routing_kernel<<<4096, 256, 0, stream>>>(attn, attn2, combined);

    // 9) x = mean_s(combined) @ Wo^T + bo
    cmean_part<<<dim3(4, 16, 8), 256, 0, stream>>>(combined, part);
    cmean_final<<<32, 256, 0, stream>>>(part, cm);
    xgemv<<<256, 256, 0, stream>>>(cm, Wo, bo, xbuf);

    // 10) hidden = x @ W_dec^T
    decode_hidden<<<1024, 64, 0, stream>>>(xbuf, codebook, instructions, hidden);

    // 11) out = hidden @ W_lm^T + b_lm
    lm_head<<<2048, 256, 0, stream>>>(Wlm, hidden, blm, out);
}

// Round 10
// 433.547 us; speedup vs baseline: 1.2349x; 1.0415x over previous
//
#include <hip/hip_runtime.h>
#include <cstdint>
#include <cstddef>

#define B_   8
#define S_   2048
#define DIN_ 1024
#define H_   1024
#define V_   50257

typedef unsigned short ushort_t;
typedef __bf16 bf16x8 __attribute__((ext_vector_type(8)));
typedef float  f32x4  __attribute__((ext_vector_type(4)));

__device__ __forceinline__ ushort_t f2bf(float x) {
    unsigned u = __float_as_uint(x);
    u = (u + 0x7fffu + ((u >> 16) & 1u)) >> 16;
    return (ushort_t)u;
}

__device__ __forceinline__ void async16(const void* g, void* s) {
    __builtin_amdgcn_global_load_lds(
        (const __attribute__((address_space(1))) unsigned int*)g,
        (__attribute__((address_space(3))) unsigned int*)s, 16, 0, 0);
}

__device__ __forceinline__ float wredmax(float v) {
#pragma unroll
    for (int o = 32; o; o >>= 1) v = fmaxf(v, __shfl_xor(v, o));
    return v;
}
__device__ __forceinline__ float wredsum(float v) {
#pragma unroll
    for (int o = 32; o; o >>= 1) v += __shfl_xor(v, o);
    return v;
}

// ---------------- merged setup: conversions + tables (one dispatch) ----------------
// blocks [0,16384): inputs f2bf | [16384,19456): Wq/Wk/Wv f2bf |
// [19456,19712): Wt transpose->bf16 | [19712,20480): b_comb | [20480,20488): pos bias
#define NB0 16384
#define NB1 19456
#define NB2 19712
#define NB3 20480
#define NB4 20488
__global__ __launch_bounds__(256)
void setup_all(const float* __restrict__ inputs,
               const float* __restrict__ Wq, const float* __restrict__ Wk,
               const float* __restrict__ Wv, const float* __restrict__ Wt,
               const float* __restrict__ bq, const float* __restrict__ bk,
               const float* __restrict__ bv, const float* __restrict__ bt,
               ushort_t* __restrict__ inbf, ushort_t* __restrict__ wqkv_bf,
               ushort_t* __restrict__ wtT, float* __restrict__ bcomb,
               float* __restrict__ pbias) {
    __shared__ float twt[64][65];
    int blk = blockIdx.x, tid = threadIdx.x;
    if (blk < NB0) {
        int i = blk * 256 + tid;  // < 4194304 float4s
        float4 f = ((const float4*)inputs)[i];
        ushort4 u;
        u.x = f2bf(f.x); u.y = f2bf(f.y); u.z = f2bf(f.z); u.w = f2bf(f.w);
        ((ushort4*)inbf)[i] = u;
    } else if (blk < NB1) {
        int i = (blk - NB0) * 256 + tid;  // < 786432
        int w = i >> 18, off = i & 262143;
        const float* src = w == 0 ? Wq : (w == 1 ? Wk : Wv);
        float4 f = ((const float4*)src)[off];
        ushort4 u;
        u.x = f2bf(f.x); u.y = f2bf(f.y); u.z = f2bf(f.z); u.w = f2bf(f.w);
        ((ushort4*)(wqkv_bf + (size_t)w * 1048576))[off] = u;
    } else if (blk < NB2) {
        int j = blk - NB1;  // 0..255
        int k0 = (j & 15) * 64, i0 = (j >> 4) * 64;
        int tx = tid & 63, ty = tid >> 6;
#pragma unroll
        for (int jj = 0; jj < 16; jj++) {
            int k = ty * 16 + jj;
            twt[k][tx] = Wt[(size_t)(k0 + k) * DIN_ + i0 + tx];
        }
        __syncthreads();
#pragma unroll
        for (int jj = 0; jj < 16; jj++) {
            int i = ty * 16 + jj;
            wtT[(size_t)(i0 + i) * H_ + k0 + tx] = f2bf(twt[tx][i]);
        }
    } else if (blk < NB3) {
        int wave = tid >> 6, lane = tid & 63;
        int j = (blk - NB2) * 4 + wave;  // 0..3071
        const float* W  = j < 1024 ? Wq : (j < 2048 ? Wk : Wv);
        const float* bb = j < 1024 ? bq : (j < 2048 ? bk : bv);
        int rowj = j & 1023;
        const float4* wr4 = (const float4*)(W + (size_t)rowj * 1024);
        const float4* bt4 = (const float4*)bt;
        float s = 0.f;
#pragma unroll
        for (int c = 0; c < 4; c++) {
            float4 w = wr4[c * 64 + lane];
            float4 b = bt4[c * 64 + lane];
            s += w.x * b.x + w.y * b.y + w.z * b.z + w.w * b.w;
        }
        s = wredsum(s);
        if (lane == 0) bcomb[j] = s + bb[rowj];
    } else {
        int k = (blk - NB3) * 256 + tid;  // < 2048
        float ang = 6.283185307179586f * (float)k / 1024.0f;
        float b = 0.f;
        b += sinf(1.f * ang) + cosf(1.f * ang);
        b += sinf(2.f * ang) + cosf(2.f * ang);
        b += sinf(4.f * ang) + cosf(4.f * ang);
        pbias[k] = b;
    }
}

// ---------------- 128^2 m97-structure GEMM — small GEMMs ----------------
template <int OUT_BF16>
__global__ __launch_bounds__(256)
void gemm_bt(const ushort_t* __restrict__ A, int lda,
             const ushort_t* __restrict__ Bt, int ldb,
             void* __restrict__ Cv, int ldc, int K, const float* __restrict__ bias) {
    int bn = blockIdx.x, bm = blockIdx.y;
    __shared__ ushort_t As[128 * 32];
    __shared__ ushort_t Bs[128 * 32];
    int tid = threadIdx.x, wave = tid >> 6, lane = tid & 63;
    int wr = wave >> 1, wc = wave & 1;
    int nkt = K >> 5;
    int srow = lane >> 2, scol = (lane & 3) * 8;
    size_t arow0 = (size_t)bm * 128, brow0 = (size_t)bn * 128;
    f32x4 acc[4][4];
#pragma unroll
    for (int m = 0; m < 4; m++)
#pragma unroll
        for (int n = 0; n < 4; n++) acc[m][n] = f32x4{0.f, 0.f, 0.f, 0.f};
    for (int kt = 0; kt < nkt; ++kt) {
        int k0 = kt * 32;
#pragma unroll
        for (int i = 0; i < 2; i++) {
            int reg = wave * 2 + i;
            int row = reg * 16 + srow;
            async16(A + (arow0 + row) * (size_t)lda + k0 + scol, (ushort_t*)As + reg * 512);
            async16(Bt + (brow0 + row) * (size_t)ldb + k0 + scol, (ushort_t*)Bs + reg * 512);
        }
        __syncthreads();
        bf16x8 af[4], bfr[4];
#pragma unroll
        for (int m = 0; m < 4; m++)
            af[m] = *(const bf16x8*)&As[(wr * 64 + m * 16 + (lane & 15)) * 32 + (lane >> 4) * 8];
#pragma unroll
        for (int n = 0; n < 4; n++)
            bfr[n] = *(const bf16x8*)&Bs[(wc * 64 + n * 16 + (lane & 15)) * 32 + (lane >> 4) * 8];
#pragma unroll
        for (int m = 0; m < 4; m++)
#pragma unroll
            for (int n = 0; n < 4; n++)
                acc[m][n] = __builtin_amdgcn_mfma_f32_16x16x32_bf16(af[m], bfr[n], acc[m][n], 0, 0, 0);
        __syncthreads();
    }
    int rl = (lane >> 4) * 4, cl = lane & 15;
#pragma unroll
    for (int m = 0; m < 4; m++)
#pragma unroll
        for (int n = 0; n < 4; n++) {
            int col = bn * 128 + wc * 64 + n * 16 + cl;
            float badd = bias ? bias[col] : 0.f;
#pragma unroll
            for (int r = 0; r < 4; r++) {
                int row = bm * 128 + wr * 64 + m * 16 + rl + r;
                float v = acc[m][n][r] + badd;
                size_t off = (size_t)row * ldc + col;
                if (OUT_BF16) ((ushort_t*)Cv)[off] = f2bf(v);
                else          ((float*)Cv)[off] = v;
            }
        }
}

// ---------------- 256^2 4-phase pipelined GEMM (r4 schedule — frozen) ----------------
// MODE 0: plain (QKV). MODE 1: causal-packed lower-triangle tiles (scores);
//         blocks x>=36 instead perform the V-transpose (qkv->vT, via Cv2 arg),
//         absorbing that work into scores' round-quantization idle capacity.
// MODE 2: PV K-split (A-set x<32: K capped 1024 -> attn; B-set x>=32: K in
//         [1024,(bm+1)*256) descending-K order -> Cv2(attn2), nkt<=16 everywhere).
// Schedule per K-tile (BK=64, 2 LDS buffers, 128KB dynamic), 4 barriers/tile:
//   p0: read af47(t)(8)             | Q0=A03xB01 | lgkm0 | BARRIER
//   p1: read bf23(t)(4)             | Q1=A47xB01 | BARRIER
//   p2: stage A(t+2,h0)             | Q2=A03xB23 | vmcnt(2) | BARRIER
//   p3: read af03,bf01(t+1)(12) | stage A(t+2,h1),B(t+2,h0),B(t+2,h1) | Q3=A47xB23 | BARRIER
// Hazard anchors: p0 lgkm0+barrier (af47 WAR), p2 vmcnt->barrier->p3 reads (t+1 RAW),
// bf23 implicit-wait before Q2 + p2-end barrier vs p3 STG_B. r3 lesson applied.
// Swizzle: 16B-slot ^= (row&7) -> measured 0 conflicts; inverse on global src.
template <int OUT_BF16, int MODE>
__global__ __launch_bounds__(512, 2)
void gemm256(const ushort_t* __restrict__ A, size_t sAb, int lda,
             const ushort_t* __restrict__ Bt, size_t sBb, int ldb,
             void* __restrict__ Cv, size_t sCb, int ldc,
             int K, const float* __restrict__ bias, int nbn, int nwg,
             float* __restrict__ Cv2) {
    extern __shared__ char lds[];
    int bz = blockIdx.y;
    int bm, bn, koff = 0, nkt;
    void* Cuse = Cv;
    size_t sCuse = sCb;
    if (MODE == 2) {
        int x = blockIdx.x;  // 0..47, no swizzle
        if (x < 32) {
            bm = x >> 2; bn = x & 3;
            int km = (bm + 1) * 256; if (km > 1024) km = 1024;
            nkt = km >> 6;
        } else {
            int j = x - 32;
            bm = 7 - (j >> 2); bn = j & 3;           // descending-K dispatch order
            koff = 1024;
            nkt = ((bm + 1) * 256 - 1024) >> 6;
            Cuse = Cv2;                               // pre-offset by -1024*ldc rows
            sCuse = (size_t)1024 * 1024;
        }
    } else if (MODE == 1) {
        int orig = blockIdx.x;
        if (orig >= 36) {
            // ---- V-transpose rider: qkv[b][s][2048+h] -> vT[b][h][s] ----
            ushort_t (*t)[66] = (ushort_t(*)[66])lds;
            ushort_t* vT = (ushort_t*)Cv2;
            const ushort_t* qkvp = A;                 // A == qkv base
            int j = orig - 36;                        // 0..63
            int tx = threadIdx.x & 63, ty = threadIdx.x >> 6;  // ty 0..7
            for (int rep = 0; rep < 8; rep++) {
                int tile = j * 8 + rep;               // 0..511
                int s0 = (tile & 31) * 64, h0 = (tile >> 5) * 64;
#pragma unroll
                for (int i = 0; i < 8; i++) {
                    int s = ty * 8 + i;
                    t[s][tx] = qkvp[((size_t)bz * S_ + s0 + s) * 3072 + 2048 + h0 + tx];
                }
                __syncthreads();
#pragma unroll
                for (int i = 0; i < 8; i++) {
                    int h = ty * 8 + i;
                    vT[((size_t)bz * H_ + h0 + h) * S_ + s0 + tx] = t[tx][h];
                }
                __syncthreads();
            }
            return;
        }
        // XCD-bijective swizzle over the 36 causal tiles (m204)
        int qq = 36 >> 3, rr8 = 36 & 7;
        int xcd = orig & 7, bidx = orig >> 3;
        int wgid = (xcd < rr8 ? xcd * (qq + 1) : rr8 * (qq + 1) + (xcd - rr8) * qq) + bidx;
        int w = wgid;
        bm = 0;
        while ((bm + 1) * (bm + 2) / 2 <= w) bm++;
        bn = w - bm * (bm + 1) / 2;
        nkt = K >> 6;
    } else {
        int orig = blockIdx.x;
        int qq = nwg >> 3, rr8 = nwg & 7;
        int xcd = orig & 7, bidx = orig >> 3;
        int wgid = (xcd < rr8 ? xcd * (qq + 1) : rr8 * (qq + 1) + (xcd - rr8) * qq) + bidx;
        bm = wgid / nbn; bn = wgid - bm * nbn;
        nkt = K >> 6;
    }

    const ushort_t* Ab = A + (size_t)bz * sAb;
    const ushort_t* Bb = Bt + (size_t)bz * sBb;
    int tid = threadIdx.x, wave = tid >> 6, lane = tid & 63;
    int wr = wave >> 2, wc = wave & 3;

    // ---- staging addressing (inverse-swizzled global source) ----
    int srow = wave * 8 + (lane >> 3);            // 0..63
    int sswz = ((lane & 7) ^ (lane >> 3)) * 8;    // k-elem offset
    const ushort_t* Ag = Ab + ((size_t)bm * 256 + srow) * (size_t)lda + sswz + koff;
    const ushort_t* Bg = Bb + ((size_t)bn * 256 + srow) * (size_t)ldb + sswz + koff;
    int sdst = wave * 1024;

    // ---- frag read addressing (swizzled) ----
    int fr = lane & 15, g = lane >> 4;
    int kx = (fr >> 2) & 1;
    int gsw = (g ^ (fr & 3)) * 16;
    int aoff = wr * 16384 + fr * 128 + gsw;                    // + bufo + mf*2048 + ksel
    int boff = 32768 + (wc >> 1) * 16384 + ((wc & 1) * 64 + fr) * 128 + gsw;
    int ks0 = kx << 6, ks1 = (kx ^ 1) << 6;                    // LDS slot for kk=0/1

    f32x4 acc[8][4];
#pragma unroll
    for (int m = 0; m < 8; m++)
#pragma unroll
        for (int n = 0; n < 4; n++) acc[m][n] = f32x4{0.f, 0.f, 0.f, 0.f};

#define STG_A(t, h, bo)                                                        \
    do {                                                                       \
        async16(Ag + (size_t)((h) * 128) * lda + (t) * 64,                     \
                lds + (bo) + (h) * 16384 + sdst);                              \
        async16(Ag + (size_t)((h) * 128 + 64) * lda + (t) * 64,                \
                lds + (bo) + (h) * 16384 + 8192 + sdst);                       \
    } while (0)
#define STG_B(t, h, bo)                                                        \
    do {                                                                       \
        async16(Bg + (size_t)((h) * 128) * ldb + (t) * 64,                     \
                lds + (bo) + 32768 + (h) * 16384 + sdst);                      \
        async16(Bg + (size_t)((h) * 128 + 64) * ldb + (t) * 64,                \
                lds + (bo) + 32768 + (h) * 16384 + 8192 + sdst);               \
    } while (0)

    // ---- prologue: tile0 -> buf0 (8 loads), tile1 -> buf1 (8 loads) ----
    STG_A(0, 0, 0); STG_A(0, 1, 0); STG_B(0, 0, 0); STG_B(0, 1, 0);
    STG_A(1, 0, 65536); STG_A(1, 1, 65536); STG_B(1, 0, 65536); STG_B(1, 1, 65536);
    asm volatile("s_waitcnt vmcnt(8)" ::: "memory");  // tile0 landed; tile1 in flight
    __builtin_amdgcn_sched_barrier(0);
    __builtin_amdgcn_s_barrier();
    __builtin_amdgcn_sched_barrier(0);

    bf16x8 af03[4][2], af47[4][2], bf01[2][2], bf23[2][2];
#pragma unroll
    for (int mf = 0; mf < 4; mf++) {
        af03[mf][0] = *(const bf16x8*)(lds + aoff + mf * 2048 + ks0);
        af03[mf][1] = *(const bf16x8*)(lds + aoff + mf * 2048 + ks1);
    }
#pragma unroll
    for (int nf = 0; nf < 2; nf++) {
        bf01[nf][0] = *(const bf16x8*)(lds + boff + nf * 2048 + ks0);
        bf01[nf][1] = *(const bf16x8*)(lds + boff + nf * 2048 + ks1);
    }

    int bufo = 0;
    for (int t = 0; t < nkt; ++t, bufo ^= 65536) {
        int nb = bufo ^ 65536;
        // ======== phase 0: read af47(t)(8); Q0 = A03 x B01 ========
#pragma unroll
        for (int mf = 0; mf < 4; mf++) {
            af47[mf][0] = *(const bf16x8*)(lds + bufo + aoff + (mf + 4) * 2048 + ks0);
            af47[mf][1] = *(const bf16x8*)(lds + bufo + aoff + (mf + 4) * 2048 + ks1);
        }
        __builtin_amdgcn_s_setprio(1);
#pragma unroll
        for (int mf = 0; mf < 4; mf++)
#pragma unroll
            for (int nf = 0; nf < 2; nf++) {
                acc[mf][nf] = __builtin_amdgcn_mfma_f32_16x16x32_bf16(af03[mf][0], bf01[nf][0], acc[mf][nf], 0, 0, 0);
                acc[mf][nf] = __builtin_amdgcn_mfma_f32_16x16x32_bf16(af03[mf][1], bf01[nf][1], acc[mf][nf], 0, 0, 0);
            }
        __builtin_amdgcn_s_setprio(0);
        __builtin_amdgcn_sched_barrier(0);
        asm volatile("s_waitcnt lgkmcnt(0)" ::: "memory");
        __builtin_amdgcn_sched_barrier(0);
        __builtin_amdgcn_s_barrier();
        __builtin_amdgcn_sched_barrier(0);

        // ======== phase 1: read bf23(t)(4); Q1 = A47 x B01 ========
#pragma unroll
        for (int nf = 0; nf < 2; nf++) {
            bf23[nf][0] = *(const bf16x8*)(lds + bufo + boff + (nf + 2) * 2048 + ks0);
            bf23[nf][1] = *(const bf16x8*)(lds + bufo + boff + (nf + 2) * 2048 + ks1);
        }
        __builtin_amdgcn_s_setprio(1);
#pragma unroll
        for (int mf = 0; mf < 4; mf++)
#pragma unroll
            for (int nf = 0; nf < 2; nf++) {
                acc[mf + 4][nf] = __builtin_amdgcn_mfma_f32_16x16x32_bf16(af47[mf][0], bf01[nf][0], acc[mf + 4][nf], 0, 0, 0);
                acc[mf + 4][nf] = __builtin_amdgcn_mfma_f32_16x16x32_bf16(af47[mf][1], bf01[nf][1], acc[mf + 4][nf], 0, 0, 0);
            }
        __builtin_amdgcn_s_setprio(0);
        __builtin_amdgcn_sched_barrier(0);
        __builtin_amdgcn_s_barrier();
        __builtin_amdgcn_sched_barrier(0);

        // ======== phase 2: stage A(t+2,h0); Q2 = A03 x B23; vmcnt ========
        if (t + 2 < nkt) STG_A(t + 2, 0, bufo);
        __builtin_amdgcn_s_setprio(1);
#pragma unroll
        for (int mf = 0; mf < 4; mf++)
#pragma unroll
            for (int nf = 0; nf < 2; nf++) {
                acc[mf][nf + 2] = __builtin_amdgcn_mfma_f32_16x16x32_bf16(af03[mf][0], bf23[nf][0], acc[mf][nf + 2], 0, 0, 0);
                acc[mf][nf + 2] = __builtin_amdgcn_mfma_f32_16x16x32_bf16(af03[mf][1], bf23[nf][1], acc[mf][nf + 2], 0, 0, 0);
            }
        __builtin_amdgcn_s_setprio(0);
        __builtin_amdgcn_sched_barrier(0);
        if (t + 1 < nkt) {
            if (t + 2 < nkt) { asm volatile("s_waitcnt vmcnt(2)" ::: "memory"); }
            else             { asm volatile("s_waitcnt vmcnt(0)" ::: "memory"); }
        }
        __builtin_amdgcn_s_barrier();   // propagates "tile t+1 landed" to all waves
        __builtin_amdgcn_sched_barrier(0);

        // ======== phase 3: read af03/bf01(t+1); stage A(t+2,h1),B(t+2); Q3 ========
        if (t + 1 < nkt) {
#pragma unroll
            for (int mf = 0; mf < 4; mf++) {
                af03[mf][0] = *(const bf16x8*)(lds + nb + aoff + mf * 2048 + ks0);
                af03[mf][1] = *(const bf16x8*)(lds + nb + aoff + mf * 2048 + ks1);
            }
#pragma unroll
            for (int nf = 0; nf < 2; nf++) {
                bf01[nf][0] = *(const bf16x8*)(lds + nb + boff + nf * 2048 + ks0);
                bf01[nf][1] = *(const bf16x8*)(lds + nb + boff + nf * 2048 + ks1);
            }
        }
        if (t + 2 < nkt) { STG_A(t + 2, 1, bufo); STG_B(t + 2, 0, bufo); STG_B(t + 2, 1, bufo); }
        __builtin_amdgcn_s_setprio(1);
#pragma unroll
        for (int mf = 0; mf < 4; mf++)
#pragma unroll
            for (int nf = 0; nf < 2; nf++) {
                acc[mf + 4][nf + 2] = __builtin_amdgcn_mfma_f32_16x16x32_bf16(af47[mf][0], bf23[nf][0], acc[mf + 4][nf + 2], 0, 0, 0);
                acc[mf + 4][nf + 2] = __builtin_amdgcn_mfma_f32_16x16x32_bf16(af47[mf][1], bf23[nf][1], acc[mf + 4][nf + 2], 0, 0, 0);
            }
        __builtin_amdgcn_s_setprio(0);
        __builtin_amdgcn_sched_barrier(0);
        __builtin_amdgcn_s_barrier();
        __builtin_amdgcn_sched_barrier(0);
    }
#undef STG_A
#undef STG_B

    int rl = (lane >> 4) * 4, cl = lane & 15;
#pragma unroll
    for (int mf = 0; mf < 8; mf++)
#pragma unroll
        for (int nf = 0; nf < 4; nf++) {
            int col = bn * 256 + wc * 64 + nf * 16 + cl;
            float badd = bias ? bias[col] : 0.f;
#pragma unroll
            for (int r = 0; r < 4; r++) {
                int row = bm * 256 + wr * 128 + mf * 16 + rl + r;
                float v = acc[mf][nf][r] + badd;
                size_t off = (size_t)bz * sCuse + (size_t)row * ldc + col;
                if (OUT_BF16) ((ushort_t*)Cuse)[off] = f2bf(v);
                else          ((float*)Cuse)[off] = v;
            }
        }
}

// ---------------- softmax rows (vectorized, register-resident) ----------------
__global__ __launch_bounds__(256)
void softmax_kernel(const float* __restrict__ scores, ushort_t* __restrict__ P,
                    const float* __restrict__ bias) {
    __shared__ float red[8];
    int q = blockIdx.x, b = blockIdx.y;
    int L = q + 1;
    int tid = threadIdx.x;
    const float4* srow4 = (const float4*)(scores + ((size_t)b * S_ + q) * S_);
    const float4* bias4 = (const float4*)bias;
    const float scale = 0.03125f;  // 1/sqrt(1024)
    int kz = ((q >> 8) + 1) * 256;  // PV reads only k < kz for this row

    int k00 = tid * 4, k01 = 1024 + tid * 4;
    float4 v0 = {0.f, 0.f, 0.f, 0.f}, v1 = {0.f, 0.f, 0.f, 0.f};
    float lm = -3e38f;
    if (k00 < kz) {
        float4 s4 = srow4[tid];
        float4 b4 = bias4[tid];
        v0.x = (k00 + 0 < L) ? s4.x * scale + b4.x : -3e38f;
        v0.y = (k00 + 1 < L) ? s4.y * scale + b4.y : -3e38f;
        v0.z = (k00 + 2 < L) ? s4.z * scale + b4.z : -3e38f;
        v0.w = (k00 + 3 < L) ? s4.w * scale + b4.w : -3e38f;
        lm = fmaxf(fmaxf(v0.x, v0.y), fmaxf(v0.z, v0.w));
    }
    if (k01 < kz) {
        float4 s4 = srow4[256 + tid];
        float4 b4 = bias4[256 + tid];
        v1.x = (k01 + 0 < L) ? s4.x * scale + b4.x : -3e38f;
        v1.y = (k01 + 1 < L) ? s4.y * scale + b4.y : -3e38f;
        v1.z = (k01 + 2 < L) ? s4.z * scale + b4.z : -3e38f;
        v1.w = (k01 + 3 < L) ? s4.w * scale + b4.w : -3e38f;
        lm = fmaxf(lm, fmaxf(fmaxf(v1.x, v1.y), fmaxf(v1.z, v1.w)));
    }
    lm = wredmax(lm);
    if ((tid & 63) == 0) red[tid >> 6] = lm;
    __syncthreads();
    float m = fmaxf(fmaxf(red[0], red[1]), fmaxf(red[2], red[3]));

    float ls = 0.f;
    if (k00 < kz) {
        v0.x = __expf(v0.x - m); v0.y = __expf(v0.y - m);
        v0.z = __expf(v0.z - m); v0.w = __expf(v0.w - m);
        ls += v0.x + v0.y + v0.z + v0.w;
    }
    if (k01 < kz) {
        v1.x = __expf(v1.x - m); v1.y = __expf(v1.y - m);
        v1.z = __expf(v1.z - m); v1.w = __expf(v1.w - m);
        ls += v1.x + v1.y + v1.z + v1.w;
    }
    ls = wredsum(ls);
    if ((tid & 63) == 0) red[4 + (tid >> 6)] = ls;
    __syncthreads();
    float invs = 1.f / (red[4] + red[5] + red[6] + red[7]);

    ushort_t* prow = P + ((size_t)b * S_ + q) * S_;
    if (k00 < kz) {
        ushort4 o;
        o.x = f2bf(v0.x * invs); o.y = f2bf(v0.y * invs);
        o.z = f2bf(v0.z * invs); o.w = f2bf(v0.w * invs);
        ((ushort4*)prow)[tid] = o;   // masked lanes hold exp(-inf)=0 -> writes 0
    }
    if (k01 < kz) {
        ushort4 o;
        o.x = f2bf(v1.x * invs); o.y = f2bf(v1.y * invs);
        o.z = f2bf(v1.z * invs); o.w = f2bf(v1.w * invs);
        ((ushort4*)prow)[256 + tid] = o;
    }
}

// ---------------- sparse routing (adds PV K-split partial for q>=1024) ----------------
__global__ __launch_bounds__(256)
void routing_kernel(const float* __restrict__ attn, const float* __restrict__ attn2,
                    ushort_t* __restrict__ combined) {
    int wave = threadIdx.x >> 6, lane = threadIdx.x & 63;
    size_t row = (size_t)blockIdx.x * 4 + wave;
    const float4* a4 = (const float4*)(attn + row * H_);
    float4 x0 = a4[lane * 4 + 0], x1 = a4[lane * 4 + 1];
    float4 x2 = a4[lane * 4 + 2], x3 = a4[lane * 4 + 3];
    int q = (int)(row & 2047);
    if (q >= 1024) {
        size_t b = row >> 11;
        const float4* a2 = (const float4*)(attn2 + ((b * 1024 + (size_t)(q - 1024)) * H_));
        float4 y0 = a2[lane * 4 + 0], y1 = a2[lane * 4 + 1];
        float4 y2 = a2[lane * 4 + 2], y3 = a2[lane * 4 + 3];
        x0.x += y0.x; x0.y += y0.y; x0.z += y0.z; x0.w += y0.w;
        x1.x += y1.x; x1.y += y1.y; x1.z += y1.z; x1.w += y1.w;
        x2.x += y2.x; x2.y += y2.y; x2.z += y2.z; x2.w += y2.w;
        x3.x += y3.x; x3.y += y3.y; x3.z += y3.z; x3.w += y3.w;
    }
    float ss = x0.x * x0.x + x0.y * x0.y + x0.z * x0.z + x0.w * x0.w
             + x1.x * x1.x + x1.y * x1.y + x1.z * x1.z + x1.w * x1.w
             + x2.x * x2.x + x2.y * x2.y + x2.z * x2.z + x2.w * x2.w
             + x3.x * x3.x + x3.y * x3.y + x3.z * x3.z + x3.w * x3.w;
    float sc = sqrtf(ss);

    float v = sc, thr = 0.f, mx = 0.f;
#pragma unroll
    for (int i = 0; i < 16; i++) {
        float mm = wredmax(v);
        if (i == 0) mx = mm;
        thr = mm;
        if (v == mm) v = -1e30f;
    }
    float e = (sc >= thr) ? __expf(sc - mx) : 0.f;
    float se = wredsum(e);
    float w = e / se;

    const float xs[16] = {x0.x, x0.y, x0.z, x0.w, x1.x, x1.y, x1.z, x1.w,
                          x2.x, x2.y, x2.z, x2.w, x3.x, x3.y, x3.z, x3.w};
    union { ushort_t u[16]; uint4 q4[2]; } pk;
#pragma unroll
    for (int j = 0; j < 16; j++) pk.u[j] = f2bf(xs[j] * w);
    uint4* dst = (uint4*)(combined + row * H_ + lane * 16);
    dst[0] = pk.q4[0];
    dst[1] = pk.q4[1];
}

// ---------------- mean over S of combined ----------------
__global__ void cmean_part(const ushort_t* __restrict__ comb, float* __restrict__ part) {
    int d = blockIdx.x * 256 + threadIdx.x;
    int sc = blockIdx.y, b = blockIdx.z;
    const ushort_t* p = comb + ((size_t)b * S_ + sc * 128) * H_ + d;
    float s = 0.f;
    for (int i = 0; i < 128; i++) s += __uint_as_float((unsigned)p[(size_t)i * H_] << 16);
    part[((size_t)b * 16 + sc) * H_ + d] = s;
}

__global__ void cmean_final(const float* __restrict__ part, float* __restrict__ cm) {
    int idx = blockIdx.x * 256 + threadIdx.x;  // 0..8191
    int b = idx >> 10, d = idx & 1023;
    float s = 0.f;
#pragma unroll
    for (int c = 0; c < 16; c++) s += part[((size_t)b * 16 + c) * DIN_ + d];
    cm[idx] = s * (1.0f / 2048.0f);
}

// ---------------- x = cmean @ Wo^T + bo (fp32) ----------------
__global__ __launch_bounds__(256)
void xgemv(const float* __restrict__ cm, const float* __restrict__ Wo,
           const float* __restrict__ bo, float* __restrict__ x) {
    int wave = threadIdx.x >> 6, lane = threadIdx.x & 63;
    int i = blockIdx.x * 4 + wave;  // 0..1023
    const float4* wr4 = (const float4*)(Wo + (size_t)i * H_);
    float4 w[4];
#pragma unroll
    for (int c = 0; c < 4; c++) w[c] = wr4[c * 64 + lane];
    float accv[B_];
#pragma unroll
    for (int b = 0; b < B_; b++) {
        const float4* c4 = (const float4*)(cm + (size_t)b * H_);
        float s = 0.f;
#pragma unroll
        for (int c = 0; c < 4; c++) {
            float4 h = c4[c * 64 + lane];
            s += w[c].x * h.x + w[c].y * h.y + w[c].z * h.z + w[c].w * h.w;
        }
        accv[b] = wredsum(s);
    }
    if (lane == 0) {
        float bi = bo[i];
#pragma unroll
        for (int b = 0; b < B_; b++) x[(size_t)b * DIN_ + i] = accv[b] + bi;
    }
}

// ---------------- demopack decoder ----------------
__global__ __launch_bounds__(64)
void decode_hidden(const float* __restrict__ x, const float* __restrict__ codebook,
                   const int* __restrict__ instr, float* __restrict__ hidden) {
    int r = blockIdx.x;
    int lane = threadIdx.x;
    int idx = instr[r * 64 + lane];
    const float4* cw = (const float4*)(codebook + (size_t)idx * 16);
    float4 c0 = cw[0], c1 = cw[1], c2 = cw[2], c3 = cw[3];
    float acc[B_];
#pragma unroll
    for (int b = 0; b < B_; b++) {
        const float4* xb = (const float4*)(x + (size_t)b * DIN_ + lane * 16);
        float4 h0 = xb[0], h1 = xb[1], h2 = xb[2], h3 = xb[3];
        acc[b] = c0.x * h0.x + c0.y * h0.y + c0.z * h0.z + c0.w * h0.w
               + c1.x * h1.x + c1.y * h1.y + c1.z * h1.z + c1.w * h1.w
               + c2.x * h2.x + c2.y * h2.y + c2.z * h2.z + c2.w * h2.w
               + c3.x * h3.x + c3.y * h3.y + c3.z * h3.z + c3.w * h3.w;
    }
#pragma unroll
    for (int b = 0; b < B_; b++) acc[b] = wredsum(acc[b]);
    if (lane == 0) {
#pragma unroll
        for (int b = 0; b < B_; b++) hidden[(size_t)b * 1024 + r] = acc[b];
    }
}

// ---------------- LM head ----------------
__global__ __launch_bounds__(256)
void lm_head(const float* __restrict__ Wlm, const float* __restrict__ hidden,
             const float* __restrict__ blm, float* __restrict__ out) {
    int wave = threadIdx.x >> 6, lane = threadIdx.x & 63;
    for (int v = blockIdx.x * 4 + wave; v < V_; v += gridDim.x * 4) {
        const float4* wrow = (const float4*)(Wlm + (size_t)v * 1024);
        float acc[B_];
#pragma unroll
        for (int b = 0; b < B_; b++) acc[b] = 0.f;
#pragma unroll
        for (int rr = 0; rr < 4; rr++) {
            float4 wv = wrow[rr * 64 + lane];
#pragma unroll
            for (int b = 0; b < B_; b++) {
                float4 hv = ((const float4*)hidden)[b * 256 + rr * 64 + lane];
                acc[b] += wv.x * hv.x + wv.y * hv.y + wv.z * hv.z + wv.w * hv.w;
            }
        }
#pragma unroll
        for (int b = 0; b < B_; b++) acc[b] = wredsum(acc[b]);
        if (lane == 0) {
            float bl = blm[v];
#pragma unroll
            for (int b = 0; b < B_; b++) out[(size_t)b * V_ + v] = acc[b] + bl;
        }
    }
}

// ---------------- host launch ----------------
extern "C" void kernel_launch(void* const* d_in, const int* in_sizes, int n_in,
                              void* d_out, int out_size, void* d_ws, size_t ws_size,
                              hipStream_t stream) {
    const float* inputs = (const float*)d_in[0];
    const float* Wt  = (const float*)d_in[1];
    const float* bt  = (const float*)d_in[2];
    const float* Wq  = (const float*)d_in[3];
    const float* bq  = (const float*)d_in[4];
    const float* Wk  = (const float*)d_in[5];
    const float* bk  = (const float*)d_in[6];
    const float* Wv  = (const float*)d_in[7];
    const float* bv  = (const float*)d_in[8];
    const float* Wo  = (const float*)d_in[9];
    const float* bo  = (const float*)d_in[10];
    const float* codebook = (const float*)d_in[11];
    const int*   instructions = (const int*)d_in[12];
    const float* Wlm = (const float*)d_in[13];
    const float* blm = (const float*)d_in[14];
    float* out = (float*)d_out;

    (void)hipFuncSetAttribute(reinterpret_cast<const void*>(&gemm256<1, 0>),
                              hipFuncAttributeMaxDynamicSharedMemorySize, 131072);
    (void)hipFuncSetAttribute(reinterpret_cast<const void*>(&gemm256<0, 1>),
                              hipFuncAttributeMaxDynamicSharedMemorySize, 131072);
    (void)hipFuncSetAttribute(reinterpret_cast<const void*>(&gemm256<0, 2>),
                              hipFuncAttributeMaxDynamicSharedMemorySize, 131072);

    const size_t MB = 1024 * 1024;
    char* ws = (char*)d_ws;
    ushort_t* wqkv_bf = (ushort_t*)(ws + 0);             // 6 MB
    ushort_t* wtT_bf  = (ushort_t*)(ws + 6 * MB);        // 2 MB
    ushort_t* wcomb   = (ushort_t*)(ws + 8 * MB);        // 6 MB
    float* bcomb  = (float*)(ws + 14 * MB);              // 12 KB
    float* pbias  = (float*)(ws + 14 * MB + 64 * 1024);  // 8 KB
    float* cm     = (float*)(ws + 14 * MB + 128 * 1024); // 32 KB
    float* xbuf   = (float*)(ws + 14 * MB + 192 * 1024); // 32 KB
    float* hidden = (float*)(ws + 14 * MB + 256 * 1024); // 32 KB
    float* part   = (float*)(ws + 14 * MB + 512 * 1024); // 512 KB
    ushort_t* inbf   = (ushort_t*)(ws + 16 * MB);   // 32 MB  [16,48)   dead after QKV
    ushort_t* qkv    = (ushort_t*)(ws + 48 * MB);   // 96 MB  [48,144)  dead after scores dispatch
    ushort_t* vT     = (ushort_t*)(ws + 144 * MB);  // 32 MB  [144,176)
    float* scores    = (float*)(ws + 176 * MB);     // 128 MB [176,304) dead after softmax
    ushort_t* P      = (ushort_t*)(ws + 304 * MB);  // 64 MB  [304,368)
    float* attn      = (float*)(ws + 48 * MB);      // 64 MB  alias over inbf/qkv
    float* attn2     = (float*)(ws + 112 * MB);     // 32 MB  alias over qkv tail
    ushort_t* combined = (ushort_t*)(ws + 176 * MB);// 32 MB  alias over scores

    // 1) merged setup: conversions + tables (single dispatch)
    setup_all<<<NB4, 256, 0, stream>>>(inputs, Wq, Wk, Wv, Wt, bq, bk, bv, bt,
                                       inbf, wqkv_bf, wtT_bf, bcomb, pbias);

    // 2) W_comb = Wqkv @ Wt  [3072,1024] bf16
    gemm_bt<1><<<dim3(8, 24), 256, 0, stream>>>(wqkv_bf, 1024, wtT_bf, 1024,
                                                wcomb, 1024, 1024, nullptr);

    // 3) qkv = inputs @ W_comb^T + b_comb  [16384,3072] bf16
    gemm256<1, 0><<<dim3(768, 1), 512, 131072, stream>>>(
        inbf, 0, 1024, wcomb, 0, 1024, qkv, 0, 3072, 1024, bcomb, 12, 768, nullptr);

    // 4) scores[b] = q @ k^T (36 causal tiles) + V-transpose rider (x>=36 -> vT)
    gemm256<0, 1><<<dim3(100, 8), 512, 131072, stream>>>(
        qkv, (size_t)S_ * 3072, 3072, qkv + 1024, (size_t)S_ * 3072, 3072,
        scores, (size_t)S_ * S_, S_, 1024, nullptr, 36, 36, (float*)vT);

    // 5) softmax -> P bf16
    softmax_kernel<<<dim3(S_, B_), 256, 0, stream>>>(scores, P, pbias);

    // 6) attn[b] = P @ vT^T fp32, K-split balanced single dispatch
    gemm256<0, 2><<<dim3(48, 8), 512, 131072, stream>>>(
        P, (size_t)S_ * S_, S_, vT, (size_t)H_ * S_, S_,
        attn, (size_t)S_ * H_, H_, S_, nullptr, 0, 0, attn2 - (size_t)1024 * 1024);

    // 7) routing (attn + attn2 partial) -> combined bf16
    routing_kernel<<<4096, 256, 0, stream>>>(attn, attn2, combined);

    // 8) x = mean_s(combined) @ Wo^T + bo
    cmean_part<<<dim3(4, 16, 8), 256, 0, stream>>>(combined, part);
    cmean_final<<<32, 256, 0, stream>>>(part, cm);
    xgemv<<<256, 256, 0, stream>>>(cm, Wo, bo, xbuf);

    // 9) hidden = x @ W_dec^T
    decode_hidden<<<1024, 64, 0, stream>>>(xbuf, codebook, instructions, hidden);

    // 10) out = hidden @ W_lm^T + b_lm
    lm_head<<<2048, 256, 0, stream>>>(Wlm, hidden, blm, out);
}